// Round 13
// baseline (248.606 us; speedup 1.0000x reference)
//
#include <hip/hip_runtime.h>

// ---------------------------------------------------------------------------
// Linformer self-attention, fp32 I/O, fp16 MFMA internally, MI355X (gfx950)
// b=4 n=4096 d=1024 h=16 dh=64 k=256  (no 1/sqrt(dh) scale per reference)
//
// Key algebra: proj_k^T (X Wk) == (proj_k^T X) Wk  -> K/V paths cost 4x less.
// This round: Q-projection FUSED into the attention kernel (per-block 128x64
// Q-tile GEMM -> LDS -> aq frags); Qh buffer + gemm_q kernel eliminated
// (-64MB HBM traffic). Xf16 lives in ws; XT + f32 partials exactly fill d_out.
// ---------------------------------------------------------------------------

typedef __fp16 f16x8 __attribute__((ext_vector_type(8)));
typedef __fp16 f16x2 __attribute__((ext_vector_type(2)));
typedef float fl4 __attribute__((ext_vector_type(4)));
typedef float f32x4 __attribute__((ext_vector_type(4)));
typedef unsigned int u32x2 __attribute__((ext_vector_type(2)));
typedef unsigned int u32x4 __attribute__((ext_vector_type(4)));

#define MFMA16(a, b, c) __builtin_amdgcn_mfma_f32_16x16x32_f16((a), (b), (c), 0, 0, 0)

__device__ __forceinline__ unsigned int pk2u(float a, float b) {
  f16x2 p = __builtin_amdgcn_cvt_pkrtz(a, b);  // low = a, high = b
  return __builtin_bit_cast(unsigned int, p);
}

__device__ __forceinline__ f16x8 pk8(fl4 a, fl4 b) {
  f16x2 p0 = __builtin_amdgcn_cvt_pkrtz(a[0], a[1]);
  f16x2 p1 = __builtin_amdgcn_cvt_pkrtz(a[2], a[3]);
  f16x2 p2 = __builtin_amdgcn_cvt_pkrtz(b[0], b[1]);
  f16x2 p3 = __builtin_amdgcn_cvt_pkrtz(b[2], b[3]);
  f16x8 r;
  r[0] = p0[0]; r[1] = p0[1]; r[2] = p1[0]; r[3] = p1[1];
  r[4] = p2[0]; r[5] = p2[1]; r[6] = p3[0]; r[7] = p3[1];
  return r;
}

__device__ __forceinline__ void gload_lds16(const __fp16* g, void* lds_base) {
  __builtin_amdgcn_global_load_lds(
      (const __attribute__((address_space(1))) void*)g,
      (__attribute__((address_space(3))) void*)lds_base, 16, 0, 0);
}

// 64B-row tile fragment read (legacy swizzle, used by bt64)
__device__ __forceinline__ f16x8 rd_swz(const __fp16* base, int row, int lg) {
  return *(const f16x8*)((const char*)base + row * 64 +
                         ((lg ^ ((row >> 1) & 3)) * 16));
}

// 128B-row tile fragment read: logical 16B chunk `ch` of `row`
__device__ __forceinline__ f16x8 rd128(const __fp16* base, int row, int ch) {
  return *(const f16x8*)((const char*)base + row * 128 +
                         ((ch ^ (row & 7)) * 16));
}

// ---------------------------------------------------------------------------
// Transpose + convert: in f32 [R][C] -> out f16 [C][R]. 32x32 tiles.
// ---------------------------------------------------------------------------
__global__ __launch_bounds__(256) void tr_cvt(
    const float* __restrict__ in, __fp16* __restrict__ out, int R, int C) {
  __shared__ float tile[32][33];
  const int t = threadIdx.x;
  const int c0 = blockIdx.x * 32, r0 = blockIdx.y * 32;
  {
    const int r = t >> 3, cg = (t & 7) * 4;
    fl4 v = *(const fl4*)(in + (size_t)(r0 + r) * C + c0 + cg);
    tile[r][cg] = v[0]; tile[r][cg + 1] = v[1];
    tile[r][cg + 2] = v[2]; tile[r][cg + 3] = v[3];
  }
  __syncthreads();
  {
    const int cc = t >> 3, rg = (t & 7) * 4;
    u32x2 p;
    p[0] = pk2u(tile[rg + 0][cc], tile[rg + 1][cc]);
    p[1] = pk2u(tile[rg + 2][cc], tile[rg + 3][cc]);
    *(u32x2*)(out + (size_t)(c0 + cc) * R + r0 + rg) = p;
  }
}

// ---------------------------------------------------------------------------
// xprep: X f32 [b][4096][1024] -> Xf16 [b][4096][1024] + XT f16 [b][1024][4096]
// ---------------------------------------------------------------------------
__global__ __launch_bounds__(256) void xprep(
    const float* __restrict__ X, __fp16* __restrict__ Xf,
    __fp16* __restrict__ XT) {
  __shared__ float tile[32][65];
  const int t = threadIdx.x;
  const int n0 = blockIdx.x * 32, d0 = blockIdx.y * 64, b = blockIdx.z;
  const float* src = X + ((size_t)b * 4096 + n0) * 1024 + d0;
  {
    const int r = t >> 3, cg = (t & 7) * 8;
    fl4 v0 = *(const fl4*)(src + (size_t)r * 1024 + cg);
    fl4 v1 = *(const fl4*)(src + (size_t)r * 1024 + cg + 4);
    *(f16x8*)(Xf + ((size_t)b * 4096 + n0 + r) * 1024 + d0 + cg) = pk8(v0, v1);
#pragma unroll
    for (int j = 0; j < 4; ++j) {
      tile[r][cg + j] = v0[j];
      tile[r][cg + 4 + j] = v1[j];
    }
  }
  __syncthreads();
  {
    const int d = t >> 2, ng = (t & 3) * 8;
    fl4 a, c;
#pragma unroll
    for (int j = 0; j < 4; ++j) {
      a[j] = tile[ng + j][d];
      c[j] = tile[ng + 4 + j][d];
    }
    *(f16x8*)(XT + ((size_t)b * 1024 + d0 + d) * 4096 + n0 + ng) = pk8(a, c);
  }
}

// ---------------------------------------------------------------------------
// Stage 1: Pk[z][kk][dd] = sum_{n in 1024-chunk c} pkT[kk][n]*XT[b][dd][n]
// (z = c*4+b). Tile 64kk x 64dd, BK=64, pure gload_lds. (unchanged, verified)
// ---------------------------------------------------------------------------
__global__ __launch_bounds__(256) void stage1_partial(
    const __fp16* __restrict__ pkT,  // [256][4096]
    const __fp16* __restrict__ pvT,  // [256][4096]
    const __fp16* __restrict__ XT,   // [b][1024][4096]
    float* __restrict__ Pk,          // [16][256][1024] f32 partials
    float* __restrict__ Pv) {        // [16][256][1024]
  __shared__ __fp16 Ak[64 * 64];
  __shared__ __fp16 Av[64 * 64];
  __shared__ __fp16 Bx[64 * 64];
  const int t = threadIdx.x;
  const int lane = t & 63, w = t >> 6;
  const int lr = lane & 15, lg = lane >> 4;
  const int fid = blockIdx.x;
  const int g = fid >> 5, s5 = fid & 31;
  const int kk0 = (s5 >> 3) * 64, p8 = s5 & 7;
  const int pr = g * 8 + p8;
  const int dd0 = (pr & 15) * 64;
  const int z = pr >> 4, b = z & 3, c = z >> 2;
  const int wr = (w >> 1) * 32, wc = (w & 1) * 32;

  f32x4 acck[2][2], accv[2][2];
#pragma unroll
  for (int i = 0; i < 2; ++i)
#pragma unroll
    for (int j = 0; j < 2; ++j) {
      acck[i][j] = (f32x4){0.f, 0.f, 0.f, 0.f};
      accv[i][j] = (f32x4){0.f, 0.f, 0.f, 0.f};
    }

  const int r8 = lane >> 3, c8 = lane & 7;
  const int ssw = ((c8 ^ r8) * 8);
  const __fp16* pkS0 = pkT + (size_t)(kk0 + w * 8 + r8) * 4096 + c * 1024 + ssw;
  const __fp16* pkS1 = pkS0 + (size_t)32 * 4096;
  const __fp16* pvS0 = pvT + (size_t)(kk0 + w * 8 + r8) * 4096 + c * 1024 + ssw;
  const __fp16* pvS1 = pvS0 + (size_t)32 * 4096;
  const __fp16* xS0 =
      XT + ((size_t)b * 1024 + dd0 + w * 8 + r8) * 4096 + c * 1024 + ssw;
  const __fp16* xS1 = xS0 + (size_t)32 * 4096;

  for (int it = 0; it < 16; ++it) {
    const int n0 = it * 64;
    __syncthreads();
    gload_lds16(pkS0 + n0, (char*)Ak + w * 1024);
    gload_lds16(pkS1 + n0, (char*)Ak + 4096 + w * 1024);
    gload_lds16(pvS0 + n0, (char*)Av + w * 1024);
    gload_lds16(pvS1 + n0, (char*)Av + 4096 + w * 1024);
    gload_lds16(xS0 + n0, (char*)Bx + w * 1024);
    gload_lds16(xS1 + n0, (char*)Bx + 4096 + w * 1024);
    __syncthreads();

#pragma unroll
    for (int s = 0; s < 2; ++s) {
      f16x8 ak[2], av[2], bx[2];
#pragma unroll
      for (int i = 0; i < 2; ++i) {
        ak[i] = rd128(Ak, wr + i * 16 + lr, s * 4 + lg);
        av[i] = rd128(Av, wr + i * 16 + lr, s * 4 + lg);
      }
#pragma unroll
      for (int j = 0; j < 2; ++j)
        bx[j] = rd128(Bx, wc + j * 16 + lr, s * 4 + lg);
#pragma unroll
      for (int i = 0; i < 2; ++i)
#pragma unroll
        for (int j = 0; j < 2; ++j) {
          acck[i][j] = MFMA16(ak[i], bx[j], acck[i][j]);
          accv[i][j] = MFMA16(av[i], bx[j], accv[i][j]);
        }
    }
  }

#pragma unroll
  for (int i = 0; i < 2; ++i)
#pragma unroll
    for (int j = 0; j < 2; ++j)
#pragma unroll
      for (int r = 0; r < 4; ++r) {
        const size_t row = (size_t)z * 256 + kk0 + wr + i * 16 + lg * 4 + r;
        const int col = dd0 + wc + j * 16 + lr;
        Pk[row * 1024 + col] = acck[i][j][r];
        Pv[row * 1024 + col] = accv[i][j][r];
      }
}

// ---------------------------------------------------------------------------
// Stage 1 reduce: Xk = f16(sum_c Pk[c*4+b]), Xv likewise. 4 f32/thread.
// ---------------------------------------------------------------------------
__global__ __launch_bounds__(256) void stage1_reduce(
    const float* __restrict__ Pk, const float* __restrict__ Pv,
    __fp16* __restrict__ Xk, __fp16* __restrict__ Xv) {
  const size_t base = ((size_t)blockIdx.x * 256 + threadIdx.x) * 4;
  const int b = (int)(base >> 18);          // 256K elems per batch slab
  const size_t rem = base & 0x3FFFFu;
  fl4 ak = (fl4){0.f, 0.f, 0.f, 0.f}, av = (fl4){0.f, 0.f, 0.f, 0.f};
#pragma unroll
  for (int c = 0; c < 4; ++c) {
    const size_t off = (((size_t)(c * 4 + b)) << 18) + rem;
    ak += *(const fl4*)(Pk + off);
    av += *(const fl4*)(Pv + off);
  }
  u32x2 pkp, pvp;
  pkp[0] = pk2u(ak[0], ak[1]); pkp[1] = pk2u(ak[2], ak[3]);
  pvp[0] = pk2u(av[0], av[1]); pvp[1] = pk2u(av[2], av[3]);
  *(u32x2*)(Xk + base) = pkp;
  *(u32x2*)(Xv + base) = pvp;
}

// ---------------------------------------------------------------------------
// Generic small BT-GEMM: C[i][j] (f16) = sum_e A[i][e] * B[j][e], E=1024.
// ---------------------------------------------------------------------------
__global__ __launch_bounds__(256) void bt64(
    const __fp16* __restrict__ A, long long bsA,
    const __fp16* __restrict__ B, long long bsB,
    __fp16* __restrict__ C, int ldC, long long bsC) {
  constexpr int E = 1024;
  __shared__ __fp16 As[64 * 32];
  __shared__ __fp16 Bs[64 * 32];
  const int t = threadIdx.x;
  const int lane = t & 63, w = t >> 6;
  const int lr = lane & 15, lg = lane >> 4;
  const int i0 = blockIdx.x * 64, j0 = blockIdx.y * 64;
  A += (size_t)blockIdx.z * (size_t)bsA;
  B += (size_t)blockIdx.z * (size_t)bsB;
  C += (size_t)blockIdx.z * (size_t)bsC;
  const int wr = (w >> 1) * 32, wc = (w & 1) * 32;

  f32x4 acc[2][2];
#pragma unroll
  for (int i = 0; i < 2; ++i)
#pragma unroll
    for (int j = 0; j < 2; ++j) acc[i][j] = (f32x4){0.f, 0.f, 0.f, 0.f};

  const int gl_row = w * 16 + (lane >> 2);
  const int gl_ch = (lane & 3) ^ ((lane >> 3) & 3);
  const __fp16* aSrc = A + (size_t)(i0 + gl_row) * E + gl_ch * 8;
  const __fp16* bSrc = B + (size_t)(j0 + gl_row) * E + gl_ch * 8;

  for (int e0 = 0; e0 < E; e0 += 32) {
    __syncthreads();
    gload_lds16(aSrc + e0, (char*)As + w * 1024);
    gload_lds16(bSrc + e0, (char*)Bs + w * 1024);
    __syncthreads();

    f16x8 af[2], bf[2];
#pragma unroll
    for (int i = 0; i < 2; ++i)
      af[i] = rd_swz(As, wr + i * 16 + lr, lg);
#pragma unroll
    for (int j = 0; j < 2; ++j)
      bf[j] = rd_swz(Bs, wc + j * 16 + lr, lg);
#pragma unroll
    for (int i = 0; i < 2; ++i)
#pragma unroll
      for (int j = 0; j < 2; ++j)
        acc[i][j] = MFMA16(af[i], bf[j], acc[i][j]);
  }

#pragma unroll
  for (int i = 0; i < 2; ++i)
#pragma unroll
    for (int j = 0; j < 2; ++j)
#pragma unroll
      for (int r = 0; r < 4; ++r) {
        const int row = i0 + wr + i * 16 + lg * 4 + r;
        const int col = j0 + wc + j * 16 + lr;
        C[(size_t)row * ldC + col] = (__fp16)acc[i][j][r];
      }
}

// ---------------------------------------------------------------------------
// Fused attention: block = (b, h, rb) via bijective XCD chunk swizzle so the
// 16 h-blocks of one (b,rb) are consecutive on one XCD (share the X tile).
// Phase A: Q-tile[128 q][64 e] = Xf[128][1024] @ WqT[h*64..+64][1024]^T
//   (BK=64, gload_lds both sides, 16 iters) -> acc -> Qs in KV LDS (K-style
//   128B-row layout) -> aq frags.
// Phase B: stage K -> swapped QK^T -> in-lane softmax -> stage V -> PV with
//   in-register P via cvt_pk + ds_bpermute -> scaled f32 output.  (verified)
// ---------------------------------------------------------------------------
__global__ __launch_bounds__(256) void attn_fused(
    const __fp16* __restrict__ Xf,   // [b*4096][1024] f16
    const __fp16* __restrict__ WqT,  // [1024][1024], WqT[e][e'] = Wq[e'][e]
    const __fp16* __restrict__ Kp,   // [b][256][1024]
    const __fp16* __restrict__ Vpt,  // [b][1024][256]
    float* __restrict__ O) {         // [b*4096][1024] f32
  __shared__ __fp16 KV[256 * 64];    // 32KB: Xs+Ws -> Qs -> K -> V^T
  const int t = threadIdx.x;
  const int lane = t & 63, w = t >> 6;
  const int lr = lane & 15, lg = lane >> 4;
  // XCD chunk swizzle: orig = (fid&7)*256 + fid>>3 ; h fastest within orig
  const int fid = blockIdx.x;
  const int orig = (fid & 7) * 256 + (fid >> 3);
  const int h = orig & 15;
  const int rb = (orig >> 4) & 31;
  const int b = orig >> 9;
  const int m0 = rb * 128 + w * 32;

  const int r8 = lane >> 3, c8 = lane & 7;
  const int ssw = (c8 ^ r8) * 8;

  // ---- Phase A: Q-tile GEMM ----
  __fp16* Xs = KV;            // [128][64] 16KB
  __fp16* Ws = KV + 8192;     // [64][64]  8KB
  const __fp16* xS = Xf + ((size_t)(b * 4096 + rb * 128) + w * 8 + r8) * 1024 + ssw;
  const __fp16* wS = WqT + (size_t)(h * 64 + w * 8 + r8) * 1024 + ssw;

  f32x4 qacc[2][4];
#pragma unroll
  for (int i = 0; i < 2; ++i)
#pragma unroll
    for (int j = 0; j < 4; ++j) qacc[i][j] = (f32x4){0.f, 0.f, 0.f, 0.f};

  for (int it = 0; it < 16; ++it) {
    const int k0 = it * 64;
    __syncthreads();
#pragma unroll
    for (int i = 0; i < 4; ++i)
      gload_lds16(xS + (size_t)i * 32 * 1024 + k0, (char*)Xs + i * 4096 + w * 1024);
#pragma unroll
    for (int i = 0; i < 2; ++i)
      gload_lds16(wS + (size_t)i * 32 * 1024 + k0, (char*)Ws + i * 4096 + w * 1024);
    __syncthreads();

#pragma unroll
    for (int s = 0; s < 2; ++s) {
      f16x8 af[2], bf[4];
#pragma unroll
      for (int mi = 0; mi < 2; ++mi)
        af[mi] = rd128(Xs, w * 32 + mi * 16 + lr, s * 4 + lg);
#pragma unroll
      for (int jj = 0; jj < 4; ++jj)
        bf[jj] = rd128(Ws, jj * 16 + lr, s * 4 + lg);
#pragma unroll
      for (int mi = 0; mi < 2; ++mi)
#pragma unroll
        for (int jj = 0; jj < 4; ++jj)
          qacc[mi][jj] = MFMA16(af[mi], bf[jj], qacc[mi][jj]);
    }
  }
  __syncthreads();  // all waves done reading Xs/Ws

  // write Q-tile (f16) into KV[0:16KB] using the K-style swizzled layout
  {
    char* Qs = (char*)KV;
#pragma unroll
    for (int mi = 0; mi < 2; ++mi)
#pragma unroll
      for (int jj = 0; jj < 4; ++jj)
#pragma unroll
        for (int r = 0; r < 4; ++r) {
          const int row = w * 32 + mi * 16 + lg * 4 + r;
          const int e = jj * 16 + lr;
          *(__fp16*)(Qs + row * 128 + (((e >> 3) ^ (row & 7)) * 16) +
                     (e & 7) * 2) = (__fp16)qacc[mi][jj][r];
        }
  }
  __syncthreads();

  f16x8 aq[2][2];
#pragma unroll
  for (int mi = 0; mi < 2; ++mi)
#pragma unroll
    for (int s = 0; s < 2; ++s)
      aq[mi][s] = rd128(KV, w * 32 + mi * 16 + lr, s * 4 + lg);
  __syncthreads();  // all aq reads done -> safe to overwrite with K

  // ---- Phase B (verified attn v3) ----
  const __fp16* Kph = Kp + (size_t)b * 256 * 1024 + h * 64;
  const __fp16* Vph = Vpt + ((size_t)b * 1024 + h * 64) * 256;

#pragma unroll
  for (int i = 0; i < 8; ++i) {
    const int kr = (i * 4 + w) * 8 + (lane >> 3);
    gload_lds16(Kph + (size_t)kr * 1024 + (((lane & 7) ^ (kr & 7)) * 8),
                (char*)KV + (i * 4 + w) * 1024);
  }
  __syncthreads();  // K staged

  f32x4 dots[2][16];
#pragma unroll
  for (int mi = 0; mi < 2; ++mi)
#pragma unroll
    for (int jt = 0; jt < 16; ++jt) dots[mi][jt] = (f32x4){0.f, 0.f, 0.f, 0.f};
#pragma unroll
  for (int jt = 0; jt < 16; ++jt) {
    const int r = jt * 16 + lr;
    f16x8 k0 = *(const f16x8*)((const char*)KV + r * 128 + ((lg ^ (r & 7)) * 16));
    f16x8 k1 =
        *(const f16x8*)((const char*)KV + r * 128 + (((4 + lg) ^ (r & 7)) * 16));
    dots[0][jt] = MFMA16(k0, aq[0][0], dots[0][jt]);
    dots[0][jt] = MFMA16(k1, aq[0][1], dots[0][jt]);
    dots[1][jt] = MFMA16(k0, aq[1][0], dots[1][jt]);
    dots[1][jt] = MFMA16(k1, aq[1][1], dots[1][jt]);
  }

  unsigned cpk[2][16][2];
  float smv[2];
#pragma unroll
  for (int mi = 0; mi < 2; ++mi) {
    float mx = -1e30f;
#pragma unroll
    for (int jt = 0; jt < 16; ++jt)
#pragma unroll
      for (int r = 0; r < 4; ++r) mx = fmaxf(mx, dots[mi][jt][r]);
    mx = fmaxf(mx, __shfl_xor(mx, 16, 64));
    mx = fmaxf(mx, __shfl_xor(mx, 32, 64));
    float sm = 0.f;
#pragma unroll
    for (int jt = 0; jt < 16; ++jt) {
#pragma unroll
      for (int r = 0; r < 4; ++r) {
        float p = __expf(dots[mi][jt][r] - mx);
        dots[mi][jt][r] = p;
        sm += p;
      }
      cpk[mi][jt][0] = pk2u(dots[mi][jt][0], dots[mi][jt][1]);
      cpk[mi][jt][1] = pk2u(dots[mi][jt][2], dots[mi][jt][3]);
    }
    sm += __shfl_xor(sm, 16, 64);
    sm += __shfl_xor(sm, 32, 64);
    smv[mi] = sm;
  }

  __syncthreads();  // all waves done reading K

#pragma unroll
  for (int i = 0; i < 8; ++i) {
    const int dd = (i * 4 + w) * 2 + (lane >> 5);
    gload_lds16(Vph + (size_t)dd * 256 + (((lane & 31) ^ (dd & 7)) * 8),
                (char*)KV + (i * 4 + w) * 1024);
  }
  __syncthreads();  // V staged

#pragma unroll
  for (int mi = 0; mi < 2; ++mi) {
    f32x4 o[4];
#pragma unroll
    for (int j = 0; j < 4; ++j) o[j] = (f32x4){0.f, 0.f, 0.f, 0.f};
#pragma unroll
    for (int ks = 0; ks < 8; ++ks) {
      u32x4 wds;
#pragma unroll
      for (int m = 0; m < 4; ++m) {
        const int addr = ((((lane & 16) >> 3) + (m >> 1)) * 16 + lr) * 4;
        const int a0 = __builtin_amdgcn_ds_bpermute(
            addr, (int)cpk[mi][ks * 2][m & 1]);
        const int a1 = __builtin_amdgcn_ds_bpermute(
            addr, (int)cpk[mi][ks * 2 + 1][m & 1]);
        wds[m] = (unsigned)((lg >> 1) ? a1 : a0);
      }
      f16x8 pa = __builtin_bit_cast(f16x8, wds);
#pragma unroll
      for (int jt2 = 0; jt2 < 4; ++jt2) {
        const int dd = jt2 * 16 + lr;
        f16x8 bv = *(const f16x8*)((const char*)KV + dd * 512 +
                                   (((ks * 4 + lg) ^ (dd & 7)) * 16));
        o[jt2] = MFMA16(pa, bv, o[jt2]);
      }
    }

    float rs[4];
#pragma unroll
    for (int r = 0; r < 4; ++r)
      rs[r] = 1.f / __shfl(smv[mi], (lane & 48) + lg * 4 + r, 64);
#pragma unroll
    for (int jt2 = 0; jt2 < 4; ++jt2)
#pragma unroll
      for (int r = 0; r < 4; ++r) {
        const size_t row = (size_t)(b * 4096 + m0 + mi * 16 + lg * 4 + r);
        O[row * 1024 + h * 64 + jt2 * 16 + lr] = o[jt2][r] * rs[r];
      }
  }
}

// ---------------------------------------------------------------------------
extern "C" void kernel_launch(void* const* d_in, const int* in_sizes, int n_in,
                              void* d_out, int out_size, void* d_ws, size_t ws_size,
                              hipStream_t stream) {
  (void)in_sizes; (void)n_in; (void)out_size; (void)ws_size;
  const float* x  = (const float*)d_in[0];
  const float* Wq = (const float*)d_in[1];
  const float* Wk = (const float*)d_in[2];
  const float* Wv = (const float*)d_in[3];
  const float* pk = (const float*)d_in[4];
  const float* pv = (const float*)d_in[5];
  float* out = (float*)d_out;

  // ws layout (f16), ~52.4 MB: Xf16 (32MB) | weights | Xk/Xv/Kp/Vpt.
  // d_out hosts XT (33.5MB) + f32 partials (33.5MB) = exact fit; attn_fused
  // only WRITES d_out (stream-ordered after all readers).
  __fp16* Xf16 = (__fp16*)d_ws;                      // 16384*1024 f16
  __fp16* WqT = Xf16 + (size_t)16384 * 1024;         // 1024*1024 each
  __fp16* WkT = WqT + (size_t)1024 * 1024;
  __fp16* WvT = WkT + (size_t)1024 * 1024;
  __fp16* pkT = WvT + (size_t)1024 * 1024;           // 256*4096 each
  __fp16* pvT = pkT + (size_t)256 * 4096;
  __fp16* Xk  = pvT + (size_t)256 * 4096;            // 4*256*1024 each
  __fp16* Xv  = Xk  + (size_t)4 * 256 * 1024;
  __fp16* Kp  = Xv  + (size_t)4 * 256 * 1024;
  __fp16* Vpt = Kp  + (size_t)4 * 256 * 1024;
  __fp16* XT = (__fp16*)d_out;                       // 4*1024*4096 f16
  float* Pk = (float*)(XT + (size_t)4 * 1024 * 4096);  // 16*256*1024 f32 each
  float* Pv = Pk + (size_t)16 * 256 * 1024;

  const dim3 bb(256);

  // 0. one-time conversions
  xprep<<<dim3(128, 16, 4), bb, 0, stream>>>(x, Xf16, XT);
  tr_cvt<<<dim3(32, 32), bb, 0, stream>>>(Wq, WqT, 1024, 1024);
  tr_cvt<<<dim3(32, 32), bb, 0, stream>>>(Wk, WkT, 1024, 1024);
  tr_cvt<<<dim3(32, 32), bb, 0, stream>>>(Wv, WvT, 1024, 1024);
  tr_cvt<<<dim3(8, 128), bb, 0, stream>>>(pk, pkT, 4096, 256);
  tr_cvt<<<dim3(8, 128), bb, 0, stream>>>(pv, pvT, 4096, 256);

  // 1. split-K low-rank projections of X^T + reduce (partials in d_out)
  stage1_partial<<<dim3(1024), bb, 0, stream>>>(pkT, pvT, XT, Pk, Pv);
  stage1_reduce<<<dim3(1024), bb, 0, stream>>>(Pk, Pv, Xk, Xv);

  // 2. Kp = Xk . Wk ; VpT = (Xv . Wv)^T
  bt64<<<dim3(4, 16, 4), bb, 0, stream>>>(Xk, 256LL * 1024, WkT, 0LL,
                                          Kp, 1024, 256LL * 1024);
  bt64<<<dim3(16, 4, 4), bb, 0, stream>>>(WvT, 0LL, Xv, 256LL * 1024,
                                          Vpt, 256, 1024LL * 256);

  // 3. fused Q-projection + attention (overwrites d_out)
  attn_fused<<<dim3(2048), bb, 0, stream>>>(Xf16, WqT, Kp, Vpt, out);
}

// Round 14
// 211.414 us; speedup vs baseline: 1.1759x; 1.1759x over previous
//
#include <hip/hip_runtime.h>

// ---------------------------------------------------------------------------
// Linformer self-attention, fp32 I/O, fp16 MFMA internally, MI355X (gfx950)
// b=4 n=4096 d=1024 h=16 dh=64 k=256  (no 1/sqrt(dh) scale per reference)
//
// Key algebra: proj_k^T (X Wk) == (proj_k^T X) Wk  -> K/V paths cost 4x less.
// Round 14: revert the failed attn fusion (r13); round-12 structure + T3
// double-buffered pipelines (issue-prefetch -> compute -> single barrier) in
// gemm_q (BK=32), stage1_partial (BK=64), bt64. attn_k/xprep unchanged.
// ---------------------------------------------------------------------------

typedef __fp16 f16x8 __attribute__((ext_vector_type(8)));
typedef __fp16 f16x2 __attribute__((ext_vector_type(2)));
typedef float fl4 __attribute__((ext_vector_type(4)));
typedef float f32x4 __attribute__((ext_vector_type(4)));
typedef unsigned int u32x2 __attribute__((ext_vector_type(2)));
typedef unsigned int u32x4 __attribute__((ext_vector_type(4)));

#define MFMA16(a, b, c) __builtin_amdgcn_mfma_f32_16x16x32_f16((a), (b), (c), 0, 0, 0)

__device__ __forceinline__ unsigned int pk2u(float a, float b) {
  f16x2 p = __builtin_amdgcn_cvt_pkrtz(a, b);  // low = a, high = b
  return __builtin_bit_cast(unsigned int, p);
}

__device__ __forceinline__ f16x8 pk8(fl4 a, fl4 b) {
  f16x2 p0 = __builtin_amdgcn_cvt_pkrtz(a[0], a[1]);
  f16x2 p1 = __builtin_amdgcn_cvt_pkrtz(a[2], a[3]);
  f16x2 p2 = __builtin_amdgcn_cvt_pkrtz(b[0], b[1]);
  f16x2 p3 = __builtin_amdgcn_cvt_pkrtz(b[2], b[3]);
  f16x8 r;
  r[0] = p0[0]; r[1] = p0[1]; r[2] = p1[0]; r[3] = p1[1];
  r[4] = p2[0]; r[5] = p2[1]; r[6] = p3[0]; r[7] = p3[1];
  return r;
}

__device__ __forceinline__ void gload_lds16(const __fp16* g, void* lds_base) {
  __builtin_amdgcn_global_load_lds(
      (const __attribute__((address_space(1))) void*)g,
      (__attribute__((address_space(3))) void*)lds_base, 16, 0, 0);
}

// 64B-row tile fragment read: logical chunk lg of `row`
__device__ __forceinline__ f16x8 rd_swz(const __fp16* base, int row, int lg) {
  return *(const f16x8*)((const char*)base + row * 64 +
                         ((lg ^ ((row >> 1) & 3)) * 16));
}

// 128B-row tile fragment read: logical 16B chunk `ch` of `row`
__device__ __forceinline__ f16x8 rd128(const __fp16* base, int row, int ch) {
  return *(const f16x8*)((const char*)base + row * 128 +
                         ((ch ^ (row & 7)) * 16));
}

// ---------------------------------------------------------------------------
// Transpose + convert: in f32 [R][C] -> out f16 [C][R]. 32x32 tiles.
// ---------------------------------------------------------------------------
__global__ __launch_bounds__(256) void tr_cvt(
    const float* __restrict__ in, __fp16* __restrict__ out, int R, int C) {
  __shared__ float tile[32][33];
  const int t = threadIdx.x;
  const int c0 = blockIdx.x * 32, r0 = blockIdx.y * 32;
  {
    const int r = t >> 3, cg = (t & 7) * 4;
    fl4 v = *(const fl4*)(in + (size_t)(r0 + r) * C + c0 + cg);
    tile[r][cg] = v[0]; tile[r][cg + 1] = v[1];
    tile[r][cg + 2] = v[2]; tile[r][cg + 3] = v[3];
  }
  __syncthreads();
  {
    const int cc = t >> 3, rg = (t & 7) * 4;
    u32x2 p;
    p[0] = pk2u(tile[rg + 0][cc], tile[rg + 1][cc]);
    p[1] = pk2u(tile[rg + 2][cc], tile[rg + 3][cc]);
    *(u32x2*)(out + (size_t)(c0 + cc) * R + r0 + rg) = p;
  }
}

// ---------------------------------------------------------------------------
// xprep: X f32 [b][4096][1024] -> Xf16 [b][4096][1024] + XT f16 [b][1024][4096]
// ---------------------------------------------------------------------------
__global__ __launch_bounds__(256) void xprep(
    const float* __restrict__ X, __fp16* __restrict__ Xf,
    __fp16* __restrict__ XT) {
  __shared__ float tile[32][65];
  const int t = threadIdx.x;
  const int n0 = blockIdx.x * 32, d0 = blockIdx.y * 64, b = blockIdx.z;
  const float* src = X + ((size_t)b * 4096 + n0) * 1024 + d0;
  {
    const int r = t >> 3, cg = (t & 7) * 8;
    fl4 v0 = *(const fl4*)(src + (size_t)r * 1024 + cg);
    fl4 v1 = *(const fl4*)(src + (size_t)r * 1024 + cg + 4);
    *(f16x8*)(Xf + ((size_t)b * 4096 + n0 + r) * 1024 + d0 + cg) = pk8(v0, v1);
#pragma unroll
    for (int j = 0; j < 4; ++j) {
      tile[r][cg + j] = v0[j];
      tile[r][cg + 4 + j] = v1[j];
    }
  }
  __syncthreads();
  {
    const int d = t >> 2, ng = (t & 3) * 8;
    fl4 a, c;
#pragma unroll
    for (int j = 0; j < 4; ++j) {
      a[j] = tile[ng + j][d];
      c[j] = tile[ng + 4 + j][d];
    }
    *(f16x8*)(XT + ((size_t)b * 1024 + d0 + d) * 4096 + n0 + ng) = pk8(a, c);
  }
}

// ---------------------------------------------------------------------------
// Stage 1 (dbuf): Pk[z][kk][dd] = sum_{n chunk c} pkT[kk][n]*XT[b][dd][n]
// (z = c*4+b). 64kk x 64dd, BK=64, 16 iters. Double-buffered: issue next-iter
// gloads -> compute current -> ONE barrier (drain hides behind 16 MFMAs).
// ---------------------------------------------------------------------------
__global__ __launch_bounds__(256) void stage1_partial(
    const __fp16* __restrict__ pkT,  // [256][4096]
    const __fp16* __restrict__ pvT,  // [256][4096]
    const __fp16* __restrict__ XT,   // [b][1024][4096]
    float* __restrict__ Pk,          // [16][256][1024] f32 partials
    float* __restrict__ Pv) {        // [16][256][1024]
  __shared__ __fp16 Ak[2][64 * 64];  // 8KB each -> 48KB total
  __shared__ __fp16 Av[2][64 * 64];
  __shared__ __fp16 Bx[2][64 * 64];
  const int t = threadIdx.x;
  const int lane = t & 63, w = t >> 6;
  const int lr = lane & 15, lg = lane >> 4;
  const int fid = blockIdx.x;
  const int g = fid >> 5, s5 = fid & 31;
  const int kk0 = (s5 >> 3) * 64, p8 = s5 & 7;
  const int pr = g * 8 + p8;
  const int dd0 = (pr & 15) * 64;
  const int z = pr >> 4, b = z & 3, c = z >> 2;
  const int wr = (w >> 1) * 32, wc = (w & 1) * 32;

  f32x4 acck[2][2], accv[2][2];
#pragma unroll
  for (int i = 0; i < 2; ++i)
#pragma unroll
    for (int j = 0; j < 2; ++j) {
      acck[i][j] = (f32x4){0.f, 0.f, 0.f, 0.f};
      accv[i][j] = (f32x4){0.f, 0.f, 0.f, 0.f};
    }

  const int r8 = lane >> 3, c8 = lane & 7;
  const int ssw = ((c8 ^ r8) * 8);
  const __fp16* pkS0 = pkT + (size_t)(kk0 + w * 8 + r8) * 4096 + c * 1024 + ssw;
  const __fp16* pkS1 = pkS0 + (size_t)32 * 4096;
  const __fp16* pvS0 = pvT + (size_t)(kk0 + w * 8 + r8) * 4096 + c * 1024 + ssw;
  const __fp16* pvS1 = pvS0 + (size_t)32 * 4096;
  const __fp16* xS0 =
      XT + ((size_t)b * 1024 + dd0 + w * 8 + r8) * 4096 + c * 1024 + ssw;
  const __fp16* xS1 = xS0 + (size_t)32 * 4096;

  // prologue: stage iter 0 into buffer 0
  gload_lds16(pkS0, (char*)Ak[0] + w * 1024);
  gload_lds16(pkS1, (char*)Ak[0] + 4096 + w * 1024);
  gload_lds16(pvS0, (char*)Av[0] + w * 1024);
  gload_lds16(pvS1, (char*)Av[0] + 4096 + w * 1024);
  gload_lds16(xS0, (char*)Bx[0] + w * 1024);
  gload_lds16(xS1, (char*)Bx[0] + 4096 + w * 1024);
  __syncthreads();

  for (int it = 0; it < 16; ++it) {
    const int cur = it & 1, nxt = cur ^ 1;
    if (it < 15) {
      const int n1 = (it + 1) * 64;
      gload_lds16(pkS0 + n1, (char*)Ak[nxt] + w * 1024);
      gload_lds16(pkS1 + n1, (char*)Ak[nxt] + 4096 + w * 1024);
      gload_lds16(pvS0 + n1, (char*)Av[nxt] + w * 1024);
      gload_lds16(pvS1 + n1, (char*)Av[nxt] + 4096 + w * 1024);
      gload_lds16(xS0 + n1, (char*)Bx[nxt] + w * 1024);
      gload_lds16(xS1 + n1, (char*)Bx[nxt] + 4096 + w * 1024);
    }
#pragma unroll
    for (int s = 0; s < 2; ++s) {
      f16x8 ak[2], av[2], bx[2];
#pragma unroll
      for (int i = 0; i < 2; ++i) {
        ak[i] = rd128(Ak[cur], wr + i * 16 + lr, s * 4 + lg);
        av[i] = rd128(Av[cur], wr + i * 16 + lr, s * 4 + lg);
      }
#pragma unroll
      for (int j = 0; j < 2; ++j)
        bx[j] = rd128(Bx[cur], wc + j * 16 + lr, s * 4 + lg);
#pragma unroll
      for (int i = 0; i < 2; ++i)
#pragma unroll
        for (int j = 0; j < 2; ++j) {
          acck[i][j] = MFMA16(ak[i], bx[j], acck[i][j]);
          accv[i][j] = MFMA16(av[i], bx[j], accv[i][j]);
        }
    }
    __syncthreads();  // prefetch drained behind compute; cur readers done
  }

#pragma unroll
  for (int i = 0; i < 2; ++i)
#pragma unroll
    for (int j = 0; j < 2; ++j)
#pragma unroll
      for (int r = 0; r < 4; ++r) {
        const size_t row = (size_t)z * 256 + kk0 + wr + i * 16 + lg * 4 + r;
        const int col = dd0 + wc + j * 16 + lr;
        Pk[row * 1024 + col] = acck[i][j][r];
        Pv[row * 1024 + col] = accv[i][j][r];
      }
}

// ---------------------------------------------------------------------------
// Stage 1 reduce: Xk = f16(sum_c Pk[c*4+b]), Xv likewise. 4 f32/thread.
// ---------------------------------------------------------------------------
__global__ __launch_bounds__(256) void stage1_reduce(
    const float* __restrict__ Pk, const float* __restrict__ Pv,
    __fp16* __restrict__ Xk, __fp16* __restrict__ Xv) {
  const size_t base = ((size_t)blockIdx.x * 256 + threadIdx.x) * 4;
  const int b = (int)(base >> 18);          // 256K elems per batch slab
  const size_t rem = base & 0x3FFFFu;
  fl4 ak = (fl4){0.f, 0.f, 0.f, 0.f}, av = (fl4){0.f, 0.f, 0.f, 0.f};
#pragma unroll
  for (int c = 0; c < 4; ++c) {
    const size_t off = (((size_t)(c * 4 + b)) << 18) + rem;
    ak += *(const fl4*)(Pk + off);
    av += *(const fl4*)(Pv + off);
  }
  u32x2 pkp, pvp;
  pkp[0] = pk2u(ak[0], ak[1]); pkp[1] = pk2u(ak[2], ak[3]);
  pvp[0] = pk2u(av[0], av[1]); pvp[1] = pk2u(av[2], av[3]);
  *(u32x2*)(Xk + base) = pkp;
  *(u32x2*)(Xv + base) = pvp;
}

// ---------------------------------------------------------------------------
// Generic small BT-GEMM (dbuf): C[i][j] = sum_e A[i][e]*B[j][e], E=1024.
// 64x64, BK=32, 32 iters, double-buffered single-barrier pipeline.
// ---------------------------------------------------------------------------
__global__ __launch_bounds__(256) void bt64(
    const __fp16* __restrict__ A, long long bsA,
    const __fp16* __restrict__ B, long long bsB,
    __fp16* __restrict__ C, int ldC, long long bsC) {
  constexpr int E = 1024;
  __shared__ __fp16 As[2][64 * 32];  // 4KB each -> 16KB
  __shared__ __fp16 Bs[2][64 * 32];
  const int t = threadIdx.x;
  const int lane = t & 63, w = t >> 6;
  const int lr = lane & 15, lg = lane >> 4;
  const int i0 = blockIdx.x * 64, j0 = blockIdx.y * 64;
  A += (size_t)blockIdx.z * (size_t)bsA;
  B += (size_t)blockIdx.z * (size_t)bsB;
  C += (size_t)blockIdx.z * (size_t)bsC;
  const int wr = (w >> 1) * 32, wc = (w & 1) * 32;

  f32x4 acc[2][2];
#pragma unroll
  for (int i = 0; i < 2; ++i)
#pragma unroll
    for (int j = 0; j < 2; ++j) acc[i][j] = (f32x4){0.f, 0.f, 0.f, 0.f};

  const int gl_row = w * 16 + (lane >> 2);
  const int gl_ch = (lane & 3) ^ ((lane >> 3) & 3);
  const __fp16* aSrc = A + (size_t)(i0 + gl_row) * E + gl_ch * 8;
  const __fp16* bSrc = B + (size_t)(j0 + gl_row) * E + gl_ch * 8;

  gload_lds16(aSrc, (char*)As[0] + w * 1024);
  gload_lds16(bSrc, (char*)Bs[0] + w * 1024);
  __syncthreads();

  for (int it = 0; it < 32; ++it) {
    const int cur = it & 1, nxt = cur ^ 1;
    if (it < 31) {
      const int e1 = (it + 1) * 32;
      gload_lds16(aSrc + e1, (char*)As[nxt] + w * 1024);
      gload_lds16(bSrc + e1, (char*)Bs[nxt] + w * 1024);
    }
    f16x8 af[2], bf[2];
#pragma unroll
    for (int i = 0; i < 2; ++i)
      af[i] = rd_swz(As[cur], wr + i * 16 + lr, lg);
#pragma unroll
    for (int j = 0; j < 2; ++j)
      bf[j] = rd_swz(Bs[cur], wc + j * 16 + lr, lg);
#pragma unroll
    for (int i = 0; i < 2; ++i)
#pragma unroll
      for (int j = 0; j < 2; ++j)
        acc[i][j] = MFMA16(af[i], bf[j], acc[i][j]);
    __syncthreads();
  }

#pragma unroll
  for (int i = 0; i < 2; ++i)
#pragma unroll
    for (int j = 0; j < 2; ++j)
#pragma unroll
      for (int r = 0; r < 4; ++r) {
        const int row = i0 + wr + i * 16 + lg * 4 + r;
        const int col = j0 + wc + j * 16 + lr;
        C[(size_t)row * ldC + col] = (__fp16)acc[i][j][r];
      }
}

// ---------------------------------------------------------------------------
// Q-path GEMM (dbuf): Qh[16384][1024] = Xf16 . WqT^T, 128x128, BK=32,
// 32 iters. Double-buffered single-barrier pipeline, pure gload_lds.
// XCD swizzle: fid = g*64 + n*8 + p -> m-tile g*8+p.
// ---------------------------------------------------------------------------
__global__ __launch_bounds__(256) void gemm_q(
    const __fp16* __restrict__ Xf,   // [16384][1024] f16
    const __fp16* __restrict__ WT,   // [1024][1024], WT[n][k] = W[k][n]
    __fp16* __restrict__ Q) {
  constexpr int K = 1024, N = 1024;
  __shared__ __fp16 Xs[2][128 * 32];  // 8KB each -> 32KB total
  __shared__ __fp16 Ws[2][128 * 32];
  const int t = threadIdx.x;
  const int lane = t & 63, w = t >> 6;
  const int lr = lane & 15, lg = lane >> 4;
  const int fid = blockIdx.x;
  const int g = fid >> 6, s6 = fid & 63;
  const int n0 = (s6 >> 3) * 128;
  const int m0 = (g * 8 + (s6 & 7)) * 128;
  const int wr = (w >> 1) * 64, wc = (w & 1) * 64;

  f32x4 acc[4][4];
#pragma unroll
  for (int i = 0; i < 4; ++i)
#pragma unroll
    for (int j = 0; j < 4; ++j) acc[i][j] = (f32x4){0.f, 0.f, 0.f, 0.f};

  // staging: call i covers rows i*64 + w*16 + (lane>>2); src chunk swizzled
  const int gl_row = w * 16 + (lane >> 2);
  const int gl_ch = (lane & 3) ^ ((lane >> 3) & 3);
  const __fp16* xS0 = Xf + (size_t)(m0 + gl_row) * K + gl_ch * 8;
  const __fp16* xS1 = xS0 + (size_t)64 * K;
  const __fp16* wS0 = WT + (size_t)(n0 + gl_row) * K + gl_ch * 8;
  const __fp16* wS1 = wS0 + (size_t)64 * K;

  gload_lds16(xS0, (char*)Xs[0] + w * 1024);
  gload_lds16(xS1, (char*)Xs[0] + 4096 + w * 1024);
  gload_lds16(wS0, (char*)Ws[0] + w * 1024);
  gload_lds16(wS1, (char*)Ws[0] + 4096 + w * 1024);
  __syncthreads();

  for (int it = 0; it < 32; ++it) {
    const int cur = it & 1, nxt = cur ^ 1;
    if (it < 31) {
      const int k1 = (it + 1) * 32;
      gload_lds16(xS0 + k1, (char*)Xs[nxt] + w * 1024);
      gload_lds16(xS1 + k1, (char*)Xs[nxt] + 4096 + w * 1024);
      gload_lds16(wS0 + k1, (char*)Ws[nxt] + w * 1024);
      gload_lds16(wS1 + k1, (char*)Ws[nxt] + 4096 + w * 1024);
    }
    f16x8 af[4], bf[4];
#pragma unroll
    for (int i = 0; i < 4; ++i)
      af[i] = rd_swz(Xs[cur], wr + i * 16 + lr, lg);
#pragma unroll
    for (int j = 0; j < 4; ++j)
      bf[j] = rd_swz(Ws[cur], wc + j * 16 + lr, lg);
#pragma unroll
    for (int i = 0; i < 4; ++i)
#pragma unroll
      for (int j = 0; j < 4; ++j)
        acc[i][j] = MFMA16(af[i], bf[j], acc[i][j]);
    __syncthreads();
  }

#pragma unroll
  for (int i = 0; i < 4; ++i)
#pragma unroll
    for (int j = 0; j < 4; ++j)
#pragma unroll
      for (int r = 0; r < 4; ++r) {
        const int row = m0 + wr + i * 16 + lg * 4 + r;
        const int col = n0 + wc + j * 16 + lr;
        Q[(size_t)row * N + col] = (__fp16)acc[i][j][r];
      }
}

// ---------------------------------------------------------------------------
// Attention v3: block = 4 waves, 128 Q-rows of one (b,h); grid 2048.
// 32KB LDS (K then V), swapped QK^T, in-register P via cvt_pk + ds_bpermute.
// (verified round 8-12, unchanged)
// ---------------------------------------------------------------------------
__global__ __launch_bounds__(256) void attn_k(
    const __fp16* __restrict__ Q,    // [b*4096][1024]
    const __fp16* __restrict__ Kp,   // [b][256][1024]
    const __fp16* __restrict__ Vpt,  // [b][1024][256]
    float* __restrict__ O) {         // [b*4096][1024] f32
  __shared__ __fp16 KV[256 * 64];    // 32KB: K tile, then V^T tile
  const int t = threadIdx.x;
  const int lane = t & 63, w = t >> 6;
  const int lr = lane & 15, lg = lane >> 4;
  const int bh = blockIdx.x >> 5, rb = blockIdx.x & 31;
  const int b = bh >> 4, h = bh & 15;
  const int m0 = rb * 128 + w * 32;

  const __fp16* Kph = Kp + (size_t)b * 256 * 1024 + h * 64;
  const __fp16* Vph = Vpt + ((size_t)b * 1024 + h * 64) * 256;
  const __fp16* Qh = Q + ((size_t)(b * 4096 + m0)) * 1024 + h * 64;

#pragma unroll
  for (int i = 0; i < 8; ++i) {
    const int kr = (i * 4 + w) * 8 + (lane >> 3);
    gload_lds16(Kph + (size_t)kr * 1024 + (((lane & 7) ^ (kr & 7)) * 8),
                (char*)KV + (i * 4 + w) * 1024);
  }

  f16x8 aq[2][2];
#pragma unroll
  for (int mi = 0; mi < 2; ++mi)
#pragma unroll
    for (int s = 0; s < 2; ++s)
      aq[mi][s] =
          *(const f16x8*)(Qh + (size_t)(mi * 16 + lr) * 1024 + s * 32 + lg * 8);

  __syncthreads();  // K staged

  f32x4 dots[2][16];
#pragma unroll
  for (int mi = 0; mi < 2; ++mi)
#pragma unroll
    for (int jt = 0; jt < 16; ++jt) dots[mi][jt] = (f32x4){0.f, 0.f, 0.f, 0.f};
#pragma unroll
  for (int jt = 0; jt < 16; ++jt) {
    const int r = jt * 16 + lr;
    f16x8 k0 = *(const f16x8*)((const char*)KV + r * 128 + ((lg ^ (r & 7)) * 16));
    f16x8 k1 =
        *(const f16x8*)((const char*)KV + r * 128 + (((4 + lg) ^ (r & 7)) * 16));
    dots[0][jt] = MFMA16(k0, aq[0][0], dots[0][jt]);
    dots[0][jt] = MFMA16(k1, aq[0][1], dots[0][jt]);
    dots[1][jt] = MFMA16(k0, aq[1][0], dots[1][jt]);
    dots[1][jt] = MFMA16(k1, aq[1][1], dots[1][jt]);
  }

  unsigned cpk[2][16][2];
  float smv[2];
#pragma unroll
  for (int mi = 0; mi < 2; ++mi) {
    float mx = -1e30f;
#pragma unroll
    for (int jt = 0; jt < 16; ++jt)
#pragma unroll
      for (int r = 0; r < 4; ++r) mx = fmaxf(mx, dots[mi][jt][r]);
    mx = fmaxf(mx, __shfl_xor(mx, 16, 64));
    mx = fmaxf(mx, __shfl_xor(mx, 32, 64));
    float sm = 0.f;
#pragma unroll
    for (int jt = 0; jt < 16; ++jt) {
#pragma unroll
      for (int r = 0; r < 4; ++r) {
        float p = __expf(dots[mi][jt][r] - mx);
        dots[mi][jt][r] = p;
        sm += p;
      }
      cpk[mi][jt][0] = pk2u(dots[mi][jt][0], dots[mi][jt][1]);
      cpk[mi][jt][1] = pk2u(dots[mi][jt][2], dots[mi][jt][3]);
    }
    sm += __shfl_xor(sm, 16, 64);
    sm += __shfl_xor(sm, 32, 64);
    smv[mi] = sm;
  }

  __syncthreads();  // all waves done reading K

#pragma unroll
  for (int i = 0; i < 8; ++i) {
    const int dd = (i * 4 + w) * 2 + (lane >> 5);
    gload_lds16(Vph + (size_t)dd * 256 + (((lane & 31) ^ (dd & 7)) * 8),
                (char*)KV + (i * 4 + w) * 1024);
  }
  __syncthreads();  // V staged

#pragma unroll
  for (int mi = 0; mi < 2; ++mi) {
    f32x4 o[4];
#pragma unroll
    for (int j = 0; j < 4; ++j) o[j] = (f32x4){0.f, 0.f, 0.f, 0.f};
#pragma unroll
    for (int ks = 0; ks < 8; ++ks) {
      u32x4 wds;
#pragma unroll
      for (int m = 0; m < 4; ++m) {
        const int addr = ((((lane & 16) >> 3) + (m >> 1)) * 16 + lr) * 4;
        const int a0 = __builtin_amdgcn_ds_bpermute(
            addr, (int)cpk[mi][ks * 2][m & 1]);
        const int a1 = __builtin_amdgcn_ds_bpermute(
            addr, (int)cpk[mi][ks * 2 + 1][m & 1]);
        wds[m] = (unsigned)((lg >> 1) ? a1 : a0);
      }
      f16x8 pa = __builtin_bit_cast(f16x8, wds);
#pragma unroll
      for (int jt2 = 0; jt2 < 4; ++jt2) {
        const int dd = jt2 * 16 + lr;
        f16x8 bv = *(const f16x8*)((const char*)KV + dd * 512 +
                                   (((ks * 4 + lg) ^ (dd & 7)) * 16));
        o[jt2] = MFMA16(pa, bv, o[jt2]);
      }
    }

    float rs[4];
#pragma unroll
    for (int r = 0; r < 4; ++r)
      rs[r] = 1.f / __shfl(smv[mi], (lane & 48) + lg * 4 + r, 64);
#pragma unroll
    for (int jt2 = 0; jt2 < 4; ++jt2)
#pragma unroll
      for (int r = 0; r < 4; ++r) {
        const size_t row = (size_t)(b * 4096 + m0 + mi * 16 + lg * 4 + r);
        O[row * 1024 + h * 64 + jt2 * 16 + lr] = o[jt2][r] * rs[r];
      }
  }
}

// ---------------------------------------------------------------------------
extern "C" void kernel_launch(void* const* d_in, const int* in_sizes, int n_in,
                              void* d_out, int out_size, void* d_ws, size_t ws_size,
                              hipStream_t stream) {
  (void)in_sizes; (void)n_in; (void)out_size; (void)ws_size;
  const float* x  = (const float*)d_in[0];
  const float* Wq = (const float*)d_in[1];
  const float* Wk = (const float*)d_in[2];
  const float* Wv = (const float*)d_in[3];
  const float* pk = (const float*)d_in[4];
  const float* pv = (const float*)d_in[5];
  float* out = (float*)d_out;

  // ws layout (f16 halfwords), total ~52.4 MB. Qh region doubles as f32
  // partials (32 MB) for stage1; gemm_q overwrites it after the reduce.
  // Xf16 + XT (33.5 MB each = 67.1 MB) live in d_out, which attn_k fully
  // overwrites at the end (all stream-ordered).
  __fp16* Qh  = (__fp16*)d_ws;                       // 16384*1024 f16
  __fp16* WqT = Qh  + (size_t)16384 * 1024;          // 1024*1024 each
  __fp16* WkT = WqT + (size_t)1024 * 1024;
  __fp16* WvT = WkT + (size_t)1024 * 1024;
  __fp16* pkT = WvT + (size_t)1024 * 1024;           // 256*4096 each
  __fp16* pvT = pkT + (size_t)256 * 4096;
  __fp16* Xk  = pvT + (size_t)256 * 4096;            // 4*256*1024 each
  __fp16* Xv  = Xk  + (size_t)4 * 256 * 1024;
  __fp16* Kp  = Xv  + (size_t)4 * 256 * 1024;
  __fp16* Vpt = Kp  + (size_t)4 * 256 * 1024;
  float* Pk = (float*)d_ws;                          // 16*256*1024 f32 each
  float* Pv = Pk + (size_t)16 * 256 * 1024;
  __fp16* Xf16 = (__fp16*)d_out;                     // 4*4096*1024 f16
  __fp16* XT   = Xf16 + (size_t)4 * 4096 * 1024;     // 4*1024*4096 f16

  const dim3 bb(256);

  // 0. one-time transposes/conversions
  xprep<<<dim3(128, 16, 4), bb, 0, stream>>>(x, Xf16, XT);
  tr_cvt<<<dim3(32, 32), bb, 0, stream>>>(Wq, WqT, 1024, 1024);
  tr_cvt<<<dim3(32, 32), bb, 0, stream>>>(Wk, WkT, 1024, 1024);
  tr_cvt<<<dim3(32, 32), bb, 0, stream>>>(Wv, WvT, 1024, 1024);
  tr_cvt<<<dim3(8, 128), bb, 0, stream>>>(pk, pkT, 4096, 256);
  tr_cvt<<<dim3(8, 128), bb, 0, stream>>>(pv, pvT, 4096, 256);

  // 1. split-K low-rank projections of X^T + reduce
  stage1_partial<<<dim3(1024), bb, 0, stream>>>(pkT, pvT, XT, Pk, Pv);
  stage1_reduce<<<dim3(1024), bb, 0, stream>>>(Pk, Pv, Xk, Xv);

  // 2. Kp = Xk . Wk ; VpT = (Xv . Wv)^T
  bt64<<<dim3(4, 16, 4), bb, 0, stream>>>(Xk, 256LL * 1024, WkT, 0LL,
                                          Kp, 1024, 256LL * 1024);
  bt64<<<dim3(16, 4, 4), bb, 0, stream>>>(WvT, 0LL, Xv, 256LL * 1024,
                                          Vpt, 256, 1024LL * 256);

  // 3. Q projection (dbuf pipeline; overwrites partials region)
  gemm_q<<<dim3(1024), bb, 0, stream>>>(Xf16, WqT, Qh);

  // 4. attention (overwrites Xf16/XT = d_out)
  attn_k<<<dim3(2048), bb, 0, stream>>>(Qh, Kp, Vpt, out);
}

// Round 15
// 195.605 us; speedup vs baseline: 1.2710x; 1.0808x over previous
//
#include <hip/hip_runtime.h>

// ---------------------------------------------------------------------------
// Linformer self-attention, fp32 I/O, fp16 MFMA internally, MI355X (gfx950)
// b=4 n=4096 d=1024 h=16 dh=64 k=256  (no 1/sqrt(dh) scale per reference)
//
// Round 15: revert GEMMs to round-12 (best) forms; attn_k rewritten on
// 32x32x16 MFMA with lane-local softmax + shfl_xor(32) P-exchange (T12),
// eliminating the 128 ds_bpermutes/thread. tr_cvt launches batched.
// ---------------------------------------------------------------------------

typedef __fp16 f16x8 __attribute__((ext_vector_type(8)));
typedef __fp16 f16x2 __attribute__((ext_vector_type(2)));
typedef float fl4 __attribute__((ext_vector_type(4)));
typedef float f32x4 __attribute__((ext_vector_type(4)));
typedef float f32x16 __attribute__((ext_vector_type(16)));
typedef unsigned int u32x2 __attribute__((ext_vector_type(2)));
typedef unsigned int u32x4 __attribute__((ext_vector_type(4)));

#define MFMA16(a, b, c) __builtin_amdgcn_mfma_f32_16x16x32_f16((a), (b), (c), 0, 0, 0)
#define MFMA32(a, b, c) __builtin_amdgcn_mfma_f32_32x32x16_f16((a), (b), (c), 0, 0, 0)

__device__ __forceinline__ unsigned int pk2u(float a, float b) {
  f16x2 p = __builtin_amdgcn_cvt_pkrtz(a, b);  // low = a, high = b
  return __builtin_bit_cast(unsigned int, p);
}

__device__ __forceinline__ f16x8 pk8(fl4 a, fl4 b) {
  f16x2 p0 = __builtin_amdgcn_cvt_pkrtz(a[0], a[1]);
  f16x2 p1 = __builtin_amdgcn_cvt_pkrtz(a[2], a[3]);
  f16x2 p2 = __builtin_amdgcn_cvt_pkrtz(b[0], b[1]);
  f16x2 p3 = __builtin_amdgcn_cvt_pkrtz(b[2], b[3]);
  f16x8 r;
  r[0] = p0[0]; r[1] = p0[1]; r[2] = p1[0]; r[3] = p1[1];
  r[4] = p2[0]; r[5] = p2[1]; r[6] = p3[0]; r[7] = p3[1];
  return r;
}

__device__ __forceinline__ void gload_lds16(const __fp16* g, void* lds_base) {
  __builtin_amdgcn_global_load_lds(
      (const __attribute__((address_space(1))) void*)g,
      (__attribute__((address_space(3))) void*)lds_base, 16, 0, 0);
}

// 64B-row tile fragment read: logical chunk lg of `row`
__device__ __forceinline__ f16x8 rd_swz(const __fp16* base, int row, int lg) {
  return *(const f16x8*)((const char*)base + row * 64 +
                         ((lg ^ ((row >> 1) & 3)) * 16));
}

// 128B-row tile fragment read: logical 16B chunk `ch` of `row`
__device__ __forceinline__ f16x8 rd128(const __fp16* base, int row, int ch) {
  return *(const f16x8*)((const char*)base + row * 128 +
                         ((ch ^ (row & 7)) * 16));
}

// ---------------------------------------------------------------------------
// Batched transpose+convert: f32 [R][C] -> f16 [C][R], 32x32 tiles, z selects.
// ---------------------------------------------------------------------------
__device__ __forceinline__ void tr_cvt_body(
    const float* in, __fp16* out, int R, int C) {
  __shared__ float tile[32][33];
  const int t = threadIdx.x;
  const int c0 = blockIdx.x * 32, r0 = blockIdx.y * 32;
  {
    const int r = t >> 3, cg = (t & 7) * 4;
    fl4 v = *(const fl4*)(in + (size_t)(r0 + r) * C + c0 + cg);
    tile[r][cg] = v[0]; tile[r][cg + 1] = v[1];
    tile[r][cg + 2] = v[2]; tile[r][cg + 3] = v[3];
  }
  __syncthreads();
  {
    const int cc = t >> 3, rg = (t & 7) * 4;
    u32x2 p;
    p[0] = pk2u(tile[rg + 0][cc], tile[rg + 1][cc]);
    p[1] = pk2u(tile[rg + 2][cc], tile[rg + 3][cc]);
    *(u32x2*)(out + (size_t)(c0 + cc) * R + r0 + rg) = p;
  }
}

__global__ __launch_bounds__(256) void tr_cvt3(
    const float* __restrict__ i0, const float* __restrict__ i1,
    const float* __restrict__ i2, __fp16* __restrict__ o0,
    __fp16* __restrict__ o1, __fp16* __restrict__ o2) {
  const float* in = (blockIdx.z == 0) ? i0 : (blockIdx.z == 1) ? i1 : i2;
  __fp16* out = (blockIdx.z == 0) ? o0 : (blockIdx.z == 1) ? o1 : o2;
  tr_cvt_body(in, out, 1024, 1024);
}

__global__ __launch_bounds__(256) void tr_cvt2(
    const float* __restrict__ i0, const float* __restrict__ i1,
    __fp16* __restrict__ o0, __fp16* __restrict__ o1) {
  const float* in = (blockIdx.z == 0) ? i0 : i1;
  __fp16* out = (blockIdx.z == 0) ? o0 : o1;
  tr_cvt_body(in, out, 4096, 256);
}

// ---------------------------------------------------------------------------
// xprep: X f32 [b][4096][1024] -> Xf16 [b][4096][1024] + XT f16 [b][1024][4096]
// ---------------------------------------------------------------------------
__global__ __launch_bounds__(256) void xprep(
    const float* __restrict__ X, __fp16* __restrict__ Xf,
    __fp16* __restrict__ XT) {
  __shared__ float tile[32][65];
  const int t = threadIdx.x;
  const int n0 = blockIdx.x * 32, d0 = blockIdx.y * 64, b = blockIdx.z;
  const float* src = X + ((size_t)b * 4096 + n0) * 1024 + d0;
  {
    const int r = t >> 3, cg = (t & 7) * 8;
    fl4 v0 = *(const fl4*)(src + (size_t)r * 1024 + cg);
    fl4 v1 = *(const fl4*)(src + (size_t)r * 1024 + cg + 4);
    *(f16x8*)(Xf + ((size_t)b * 4096 + n0 + r) * 1024 + d0 + cg) = pk8(v0, v1);
#pragma unroll
    for (int j = 0; j < 4; ++j) {
      tile[r][cg + j] = v0[j];
      tile[r][cg + 4 + j] = v1[j];
    }
  }
  __syncthreads();
  {
    const int d = t >> 2, ng = (t & 3) * 8;
    fl4 a, c;
#pragma unroll
    for (int j = 0; j < 4; ++j) {
      a[j] = tile[ng + j][d];
      c[j] = tile[ng + 4 + j][d];
    }
    *(f16x8*)(XT + ((size_t)b * 1024 + d0 + d) * 4096 + n0 + ng) = pk8(a, c);
  }
}

// ---------------------------------------------------------------------------
// Stage 1 (r12): Pk[z][kk][dd] = sum_{n chunk c} pkT[kk][n]*XT[b][dd][n]
// 64kk x 64dd, BK=64, 16 iters, pure gload_lds, single buffer.
// ---------------------------------------------------------------------------
__global__ __launch_bounds__(256) void stage1_partial(
    const __fp16* __restrict__ pkT,  // [256][4096]
    const __fp16* __restrict__ pvT,  // [256][4096]
    const __fp16* __restrict__ XT,   // [b][1024][4096]
    float* __restrict__ Pk,          // [16][256][1024] f32 partials
    float* __restrict__ Pv) {        // [16][256][1024]
  __shared__ __fp16 Ak[64 * 64];
  __shared__ __fp16 Av[64 * 64];
  __shared__ __fp16 Bx[64 * 64];
  const int t = threadIdx.x;
  const int lane = t & 63, w = t >> 6;
  const int lr = lane & 15, lg = lane >> 4;
  const int fid = blockIdx.x;
  const int g = fid >> 5, s5 = fid & 31;
  const int kk0 = (s5 >> 3) * 64, p8 = s5 & 7;
  const int pr = g * 8 + p8;
  const int dd0 = (pr & 15) * 64;
  const int z = pr >> 4, b = z & 3, c = z >> 2;
  const int wr = (w >> 1) * 32, wc = (w & 1) * 32;

  f32x4 acck[2][2], accv[2][2];
#pragma unroll
  for (int i = 0; i < 2; ++i)
#pragma unroll
    for (int j = 0; j < 2; ++j) {
      acck[i][j] = (f32x4){0.f, 0.f, 0.f, 0.f};
      accv[i][j] = (f32x4){0.f, 0.f, 0.f, 0.f};
    }

  const int r8 = lane >> 3, c8 = lane & 7;
  const int ssw = ((c8 ^ r8) * 8);
  const __fp16* pkS0 = pkT + (size_t)(kk0 + w * 8 + r8) * 4096 + c * 1024 + ssw;
  const __fp16* pkS1 = pkS0 + (size_t)32 * 4096;
  const __fp16* pvS0 = pvT + (size_t)(kk0 + w * 8 + r8) * 4096 + c * 1024 + ssw;
  const __fp16* pvS1 = pvS0 + (size_t)32 * 4096;
  const __fp16* xS0 =
      XT + ((size_t)b * 1024 + dd0 + w * 8 + r8) * 4096 + c * 1024 + ssw;
  const __fp16* xS1 = xS0 + (size_t)32 * 4096;

  for (int it = 0; it < 16; ++it) {
    const int n0 = it * 64;
    __syncthreads();
    gload_lds16(pkS0 + n0, (char*)Ak + w * 1024);
    gload_lds16(pkS1 + n0, (char*)Ak + 4096 + w * 1024);
    gload_lds16(pvS0 + n0, (char*)Av + w * 1024);
    gload_lds16(pvS1 + n0, (char*)Av + 4096 + w * 1024);
    gload_lds16(xS0 + n0, (char*)Bx + w * 1024);
    gload_lds16(xS1 + n0, (char*)Bx + 4096 + w * 1024);
    __syncthreads();

#pragma unroll
    for (int s = 0; s < 2; ++s) {
      f16x8 ak[2], av[2], bx[2];
#pragma unroll
      for (int i = 0; i < 2; ++i) {
        ak[i] = rd128(Ak, wr + i * 16 + lr, s * 4 + lg);
        av[i] = rd128(Av, wr + i * 16 + lr, s * 4 + lg);
      }
#pragma unroll
      for (int j = 0; j < 2; ++j)
        bx[j] = rd128(Bx, wc + j * 16 + lr, s * 4 + lg);
#pragma unroll
      for (int i = 0; i < 2; ++i)
#pragma unroll
        for (int j = 0; j < 2; ++j) {
          acck[i][j] = MFMA16(ak[i], bx[j], acck[i][j]);
          accv[i][j] = MFMA16(av[i], bx[j], accv[i][j]);
        }
    }
  }

#pragma unroll
  for (int i = 0; i < 2; ++i)
#pragma unroll
    for (int j = 0; j < 2; ++j)
#pragma unroll
      for (int r = 0; r < 4; ++r) {
        const size_t row = (size_t)z * 256 + kk0 + wr + i * 16 + lg * 4 + r;
        const int col = dd0 + wc + j * 16 + lr;
        Pk[row * 1024 + col] = acck[i][j][r];
        Pv[row * 1024 + col] = accv[i][j][r];
      }
}

// ---------------------------------------------------------------------------
// Stage 1 reduce: Xk = f16(sum_c Pk[c*4+b]), Xv likewise. 4 f32/thread.
// ---------------------------------------------------------------------------
__global__ __launch_bounds__(256) void stage1_reduce(
    const float* __restrict__ Pk, const float* __restrict__ Pv,
    __fp16* __restrict__ Xk, __fp16* __restrict__ Xv) {
  const size_t base = ((size_t)blockIdx.x * 256 + threadIdx.x) * 4;
  const int b = (int)(base >> 18);          // 256K elems per batch slab
  const size_t rem = base & 0x3FFFFu;
  fl4 ak = (fl4){0.f, 0.f, 0.f, 0.f}, av = (fl4){0.f, 0.f, 0.f, 0.f};
#pragma unroll
  for (int c = 0; c < 4; ++c) {
    const size_t off = (((size_t)(c * 4 + b)) << 18) + rem;
    ak += *(const fl4*)(Pk + off);
    av += *(const fl4*)(Pv + off);
  }
  u32x2 pkp, pvp;
  pkp[0] = pk2u(ak[0], ak[1]); pkp[1] = pk2u(ak[2], ak[3]);
  pvp[0] = pk2u(av[0], av[1]); pvp[1] = pk2u(av[2], av[3]);
  *(u32x2*)(Xk + base) = pkp;
  *(u32x2*)(Xv + base) = pvp;
}

// ---------------------------------------------------------------------------
// Generic small BT-GEMM (r12): C[i][j] = sum_e A[i][e]*B[j][e], E=1024.
// ---------------------------------------------------------------------------
__global__ __launch_bounds__(256) void bt64(
    const __fp16* __restrict__ A, long long bsA,
    const __fp16* __restrict__ B, long long bsB,
    __fp16* __restrict__ C, int ldC, long long bsC) {
  constexpr int E = 1024;
  __shared__ __fp16 As[64 * 32];
  __shared__ __fp16 Bs[64 * 32];
  const int t = threadIdx.x;
  const int lane = t & 63, w = t >> 6;
  const int lr = lane & 15, lg = lane >> 4;
  const int i0 = blockIdx.x * 64, j0 = blockIdx.y * 64;
  A += (size_t)blockIdx.z * (size_t)bsA;
  B += (size_t)blockIdx.z * (size_t)bsB;
  C += (size_t)blockIdx.z * (size_t)bsC;
  const int wr = (w >> 1) * 32, wc = (w & 1) * 32;

  f32x4 acc[2][2];
#pragma unroll
  for (int i = 0; i < 2; ++i)
#pragma unroll
    for (int j = 0; j < 2; ++j) acc[i][j] = (f32x4){0.f, 0.f, 0.f, 0.f};

  const int gl_row = w * 16 + (lane >> 2);
  const int gl_ch = (lane & 3) ^ ((lane >> 3) & 3);
  const __fp16* aSrc = A + (size_t)(i0 + gl_row) * E + gl_ch * 8;
  const __fp16* bSrc = B + (size_t)(j0 + gl_row) * E + gl_ch * 8;

  for (int e0 = 0; e0 < E; e0 += 32) {
    __syncthreads();
    gload_lds16(aSrc + e0, (char*)As + w * 1024);
    gload_lds16(bSrc + e0, (char*)Bs + w * 1024);
    __syncthreads();

    f16x8 af[2], bf[2];
#pragma unroll
    for (int i = 0; i < 2; ++i)
      af[i] = rd_swz(As, wr + i * 16 + lr, lg);
#pragma unroll
    for (int j = 0; j < 2; ++j)
      bf[j] = rd_swz(Bs, wc + j * 16 + lr, lg);
#pragma unroll
    for (int i = 0; i < 2; ++i)
#pragma unroll
      for (int j = 0; j < 2; ++j)
        acc[i][j] = MFMA16(af[i], bf[j], acc[i][j]);
  }

#pragma unroll
  for (int i = 0; i < 2; ++i)
#pragma unroll
    for (int j = 0; j < 2; ++j)
#pragma unroll
      for (int r = 0; r < 4; ++r) {
        const int row = i0 + wr + i * 16 + lg * 4 + r;
        const int col = j0 + wc + j * 16 + lr;
        C[(size_t)row * ldC + col] = (__fp16)acc[i][j][r];
      }
}

// ---------------------------------------------------------------------------
// Q-path GEMM (r12): Qh = Xf16 . WqT^T, 128x128, BK=64, 16 iters, pure
// gload_lds, single buffer. XCD swizzle: fid = g*64 + n*8 + p.
// ---------------------------------------------------------------------------
__global__ __launch_bounds__(256) void gemm_q(
    const __fp16* __restrict__ Xf,   // [16384][1024] f16
    const __fp16* __restrict__ WT,   // [1024][1024], WT[n][k] = W[k][n]
    __fp16* __restrict__ Q) {
  constexpr int K = 1024, N = 1024;
  __shared__ __fp16 Xs[128 * 64];  // 16KB
  __shared__ __fp16 Ws[128 * 64];
  const int t = threadIdx.x;
  const int lane = t & 63, w = t >> 6;
  const int lr = lane & 15, lg = lane >> 4;
  const int fid = blockIdx.x;
  const int g = fid >> 6, s6 = fid & 63;
  const int n0 = (s6 >> 3) * 128;
  const int m0 = (g * 8 + (s6 & 7)) * 128;
  const int wr = (w >> 1) * 64, wc = (w & 1) * 64;

  f32x4 acc[4][4];
#pragma unroll
  for (int i = 0; i < 4; ++i)
#pragma unroll
    for (int j = 0; j < 4; ++j) acc[i][j] = (f32x4){0.f, 0.f, 0.f, 0.f};

  const int r8 = lane >> 3, c8 = lane & 7;
  const int ssw = ((c8 ^ r8) * 8);
  const __fp16* xS = Xf + (size_t)(m0 + w * 8 + r8) * K + ssw;
  const __fp16* wS = WT + (size_t)(n0 + w * 8 + r8) * K + ssw;

  for (int it = 0; it < 16; ++it) {
    const int k0 = it * 64;
    __syncthreads();
#pragma unroll
    for (int i = 0; i < 4; ++i) {
      gload_lds16(xS + (size_t)i * 32 * K + k0, (char*)Xs + i * 4096 + w * 1024);
      gload_lds16(wS + (size_t)i * 32 * K + k0, (char*)Ws + i * 4096 + w * 1024);
    }
    __syncthreads();

#pragma unroll
    for (int s = 0; s < 2; ++s) {
      f16x8 af[4], bf[4];
#pragma unroll
      for (int i = 0; i < 4; ++i)
        af[i] = rd128(Xs, wr + i * 16 + lr, s * 4 + lg);
#pragma unroll
      for (int j = 0; j < 4; ++j)
        bf[j] = rd128(Ws, wc + j * 16 + lr, s * 4 + lg);
#pragma unroll
      for (int i = 0; i < 4; ++i)
#pragma unroll
        for (int j = 0; j < 4; ++j)
          acc[i][j] = MFMA16(af[i], bf[j], acc[i][j]);
    }
  }

#pragma unroll
  for (int i = 0; i < 4; ++i)
#pragma unroll
    for (int j = 0; j < 4; ++j)
#pragma unroll
      for (int r = 0; r < 4; ++r) {
        const int row = m0 + wr + i * 16 + lg * 4 + r;
        const int col = n0 + wc + j * 16 + lr;
        Q[(size_t)row * N + col] = (__fp16)acc[i][j][r];
      }
}

// ---------------------------------------------------------------------------
// Attention v4 (32x32 MFMA, T12): block = 4 waves x 32 q-rows, grid 2048.
// Swapped QK^T via mfma32: dots D-layout col=lane&31 = q (lane-local rows).
// Softmax fully in-lane (+1 shfl_xor(32) for the partner half). P scaled by
// 1/sm, packed to f16 pairs; PV A-frags assembled with 2 shfl_xor(32) per
// k-step (no ds_bpermute). K/V LDS staging identical to verified r12 kernel.
// ---------------------------------------------------------------------------
__global__ __launch_bounds__(256) void attn_k(
    const __fp16* __restrict__ Q,    // [b*4096][1024]
    const __fp16* __restrict__ Kp,   // [b][256][1024]
    const __fp16* __restrict__ Vpt,  // [b][1024][256]
    float* __restrict__ O) {         // [b*4096][1024] f32
  __shared__ __fp16 KV[256 * 64];    // 32KB: K tile, then V^T tile
  const int t = threadIdx.x;
  const int lane = t & 63, w = t >> 6;
  const int l31 = lane & 31, b5 = lane >> 5;
  const int bh = blockIdx.x >> 5, rb = blockIdx.x & 31;
  const int b = bh >> 4, h = bh & 15;
  const int m0 = rb * 128 + w * 32;

  const __fp16* Kph = Kp + (size_t)b * 256 * 1024 + h * 64;
  const __fp16* Vph = Vpt + ((size_t)b * 1024 + h * 64) * 256;
  const __fp16* Qh = Q + ((size_t)(b * 4096 + m0)) * 1024 + h * 64;

  // ---- stage K (verified): rows kk, 128B rows, src chunk pre-swizzle kr&7
#pragma unroll
  for (int i = 0; i < 8; ++i) {
    const int kr = (i * 4 + w) * 8 + (lane >> 3);
    gload_lds16(Kph + (size_t)kr * 1024 + (((lane & 7) ^ (kr & 7)) * 8),
                (char*)KV + (i * 4 + w) * 1024);
  }

  // Q B-frags: col = q = l31, k = dd = s*16 + b5*8 + j
  f16x8 bq[4];
#pragma unroll
  for (int s = 0; s < 4; ++s)
    bq[s] = *(const f16x8*)(Qh + (size_t)l31 * 1024 + s * 16 + b5 * 8);

  __syncthreads();  // K staged

  // ---- swapped QK^T: dots[tile] = S^T[kk = tile*32 + D-row][q = l31]
  f32x16 dots[8];
#pragma unroll
  for (int tile = 0; tile < 8; ++tile) {
    f32x16 d = {};
#pragma unroll
    for (int s = 0; s < 4; ++s) {
      f16x8 ka = rd128(KV, tile * 32 + l31, s * 2 + b5);
      d = MFMA32(ka, bq[s], d);
    }
    dots[tile] = d;
  }

  // ---- softmax: all values in (lane, lane^32) belong to row q = l31
  float mx = -1e30f;
#pragma unroll
  for (int tile = 0; tile < 8; ++tile)
#pragma unroll
    for (int r = 0; r < 16; ++r) mx = fmaxf(mx, dots[tile][r]);
  mx = fmaxf(mx, __shfl_xor(mx, 32, 64));
  float sm = 0.f;
#pragma unroll
  for (int tile = 0; tile < 8; ++tile)
#pragma unroll
    for (int r = 0; r < 16; ++r) {
      float p = __expf(dots[tile][r] - mx);
      dots[tile][r] = p;
      sm += p;
    }
  sm += __shfl_xor(sm, 32, 64);
  const float rs = 1.f / sm;

  // ---- pack P*rs to f16; exchange halves with partner lane (lane^32).
  // reg r of tile: kk_local = (r&3) + 8*(r>>2) + 4*b5.
  unsigned pkw[8][8];
#pragma unroll
  for (int tile = 0; tile < 8; ++tile)
#pragma unroll
    for (int half = 0; half < 2; ++half) {
      const int rb8 = half * 8;
      const unsigned A0 = pk2u(dots[tile][rb8 + 0] * rs, dots[tile][rb8 + 1] * rs);
      const unsigned A1 = pk2u(dots[tile][rb8 + 2] * rs, dots[tile][rb8 + 3] * rs);
      const unsigned B0 = pk2u(dots[tile][rb8 + 4] * rs, dots[tile][rb8 + 5] * rs);
      const unsigned B1 = pk2u(dots[tile][rb8 + 6] * rs, dots[tile][rb8 + 7] * rs);
      const unsigned s0 = __shfl_xor(b5 ? A0 : B0, 32, 64);
      const unsigned s1 = __shfl_xor(b5 ? A1 : B1, 32, 64);
      pkw[tile][half * 4 + 0] = b5 ? s0 : A0;
      pkw[tile][half * 4 + 1] = b5 ? s1 : A1;
      pkw[tile][half * 4 + 2] = b5 ? B0 : s0;
      pkw[tile][half * 4 + 3] = b5 ? B1 : s1;
    }

  __syncthreads();  // all waves done reading K

  // ---- stage V^T (verified): rows dd, 512B rows, src chunk swizzle dd&7
#pragma unroll
  for (int i = 0; i < 8; ++i) {
    const int dd = (i * 4 + w) * 2 + (lane >> 5);
    gload_lds16(Vph + (size_t)dd * 256 + (((lane & 31) ^ (dd & 7)) * 8),
                (char*)KV + (i * 4 + w) * 1024);
  }
  __syncthreads();  // V staged

  // ---- PV: out[q][dd] = sum_kk P[q][kk] V[kk][dd], mfma32 per (kstep, dt)
  f32x16 o[2];
  o[0] = (f32x16){};
  o[1] = (f32x16){};
#pragma unroll
  for (int tile = 0; tile < 8; ++tile)
#pragma unroll
    for (int half = 0; half < 2; ++half) {
      u32x4 wds;
#pragma unroll
      for (int m = 0; m < 4; ++m) wds[m] = pkw[tile][half * 4 + m];
      f16x8 pa = __builtin_bit_cast(f16x8, wds);
      const int ks = tile * 2 + half;
#pragma unroll
      for (int dt = 0; dt < 2; ++dt) {
        const int dd = dt * 32 + l31;
        f16x8 bv = *(const f16x8*)(
            (const char*)KV + dd * 512 + (((ks * 2 + b5) ^ (dd & 7)) * 16));
        o[dt] = MFMA32(pa, bv, o[dt]);
      }
    }

  // ---- store: D rows q = (r&3)+8*(r>>2)+4*b5, col = dt*32 + l31
#pragma unroll
  for (int dt = 0; dt < 2; ++dt)
#pragma unroll
    for (int r = 0; r < 16; ++r) {
      const int q = (r & 3) + 8 * (r >> 2) + 4 * b5;
      const size_t row = (size_t)(b * 4096 + m0 + q);
      O[row * 1024 + h * 64 + dt * 32 + l31] = o[dt][r];
    }
}

// ---------------------------------------------------------------------------
extern "C" void kernel_launch(void* const* d_in, const int* in_sizes, int n_in,
                              void* d_out, int out_size, void* d_ws, size_t ws_size,
                              hipStream_t stream) {
  (void)in_sizes; (void)n_in; (void)out_size; (void)ws_size;
  const float* x  = (const float*)d_in[0];
  const float* Wq = (const float*)d_in[1];
  const float* Wk = (const float*)d_in[2];
  const float* Wv = (const float*)d_in[3];
  const float* pk = (const float*)d_in[4];
  const float* pv = (const float*)d_in[5];
  float* out = (float*)d_out;

  // ws layout (f16 halfwords), ~52.4 MB. Qh region doubles as f32 partials
  // (32 MB) for stage1; gemm_q overwrites it after the reduce. Xf16 + XT
  // (33.5 MB each) live in d_out, fully overwritten by attn_k at the end.
  __fp16* Qh  = (__fp16*)d_ws;                       // 16384*1024 f16
  __fp16* WqT = Qh  + (size_t)16384 * 1024;          // 1024*1024 each
  __fp16* WkT = WqT + (size_t)1024 * 1024;
  __fp16* WvT = WkT + (size_t)1024 * 1024;
  __fp16* pkT = WvT + (size_t)1024 * 1024;           // 256*4096 each
  __fp16* pvT = pkT + (size_t)256 * 4096;
  __fp16* Xk  = pvT + (size_t)256 * 4096;            // 4*256*1024 each
  __fp16* Xv  = Xk  + (size_t)4 * 256 * 1024;
  __fp16* Kp  = Xv  + (size_t)4 * 256 * 1024;
  __fp16* Vpt = Kp  + (size_t)4 * 256 * 1024;
  float* Pk = (float*)d_ws;                          // 16*256*1024 f32 each
  float* Pv = Pk + (size_t)16 * 256 * 1024;
  __fp16* Xf16 = (__fp16*)d_out;                     // 4*4096*1024 f16
  __fp16* XT   = Xf16 + (size_t)4 * 4096 * 1024;     // 4*1024*4096 f16

  const dim3 bb(256);

  // 0. one-time conversions (batched)
  xprep<<<dim3(128, 16, 4), bb, 0, stream>>>(x, Xf16, XT);
  tr_cvt3<<<dim3(32, 32, 3), bb, 0, stream>>>(Wq, Wk, Wv, WqT, WkT, WvT);
  tr_cvt2<<<dim3(8, 128, 2), bb, 0, stream>>>(pk, pv, pkT, pvT);

  // 1. split-K low-rank projections of X^T + reduce
  stage1_partial<<<dim3(1024), bb, 0, stream>>>(pkT, pvT, XT, Pk, Pv);
  stage1_reduce<<<dim3(1024), bb, 0, stream>>>(Pk, Pv, Xk, Xv);

  // 2. Kp = Xk . Wk ; VpT = (Xv . Wv)^T
  bt64<<<dim3(4, 16, 4), bb, 0, stream>>>(Xk, 256LL * 1024, WkT, 0LL,
                                          Kp, 1024, 256LL * 1024);
  bt64<<<dim3(16, 4, 4), bb, 0, stream>>>(WvT, 0LL, Xv, 256LL * 1024,
                                          Vpt, 256, 1024LL * 256);

  // 3. Q projection (r12 form; overwrites partials region)
  gemm_q<<<dim3(1024), bb, 0, stream>>>(Xf16, WqT, Qh);

  // 4. attention (32x32 MFMA; overwrites Xf16/XT = d_out)
  attn_k<<<dim3(2048), bb, 0, stream>>>(Qh, Kp, Vpt, out);
}

// Round 16
// 166.676 us; speedup vs baseline: 1.4916x; 1.1736x over previous
//
#include <hip/hip_runtime.h>

// ---------------------------------------------------------------------------
// Linformer self-attention, fp32 I/O, fp16 MFMA internally, MI355X (gfx950)
// b=4 n=4096 d=1024 h=16 dh=64 k=256  (no 1/sqrt(dh) scale per reference)
//
// Round 16: r12 configuration (best, 189.2) with: attn_k = verified r12
// 16x16 kernel; f16 stage1 partials; bt64 at BK=64, both calls merged into
// one launch; all prep (xprep + weight/proj transposes) merged into one.
// ---------------------------------------------------------------------------

typedef __fp16 f16x8 __attribute__((ext_vector_type(8)));
typedef __fp16 f16x2 __attribute__((ext_vector_type(2)));
typedef float fl4 __attribute__((ext_vector_type(4)));
typedef float f32x4 __attribute__((ext_vector_type(4)));
typedef unsigned int u32x2 __attribute__((ext_vector_type(2)));
typedef unsigned int u32x4 __attribute__((ext_vector_type(4)));

#define MFMA16(a, b, c) __builtin_amdgcn_mfma_f32_16x16x32_f16((a), (b), (c), 0, 0, 0)

__device__ __forceinline__ unsigned int pk2u(float a, float b) {
  f16x2 p = __builtin_amdgcn_cvt_pkrtz(a, b);  // low = a, high = b
  return __builtin_bit_cast(unsigned int, p);
}

__device__ __forceinline__ f16x8 pk8(fl4 a, fl4 b) {
  f16x2 p0 = __builtin_amdgcn_cvt_pkrtz(a[0], a[1]);
  f16x2 p1 = __builtin_amdgcn_cvt_pkrtz(a[2], a[3]);
  f16x2 p2 = __builtin_amdgcn_cvt_pkrtz(b[0], b[1]);
  f16x2 p3 = __builtin_amdgcn_cvt_pkrtz(b[2], b[3]);
  f16x8 r;
  r[0] = p0[0]; r[1] = p0[1]; r[2] = p1[0]; r[3] = p1[1];
  r[4] = p2[0]; r[5] = p2[1]; r[6] = p3[0]; r[7] = p3[1];
  return r;
}

__device__ __forceinline__ void gload_lds16(const __fp16* g, void* lds_base) {
  __builtin_amdgcn_global_load_lds(
      (const __attribute__((address_space(1))) void*)g,
      (__attribute__((address_space(3))) void*)lds_base, 16, 0, 0);
}

// 128B-row tile fragment read: logical 16B chunk `ch` of `row`
__device__ __forceinline__ f16x8 rd128(const __fp16* base, int row, int ch) {
  return *(const f16x8*)((const char*)base + row * 128 +
                         ((ch ^ (row & 7)) * 16));
}

// ---------------------------------------------------------------------------
// prep: one launch. Blocks [0,8192): xprep (X f32 -> Xf16 + XT f16).
// [8192,11264): 3x W 1024x1024 transpose+cvt. [11264,13312): 2x proj
// 4096x256 transpose+cvt.
// ---------------------------------------------------------------------------
__device__ __forceinline__ void tr_cvt_body(
    float* tile, const float* in, __fp16* out, int R, int C, int bx, int by) {
  const int t = threadIdx.x;
  const int c0 = bx * 32, r0 = by * 32;
  {
    const int r = t >> 3, cg = (t & 7) * 4;
    fl4 v = *(const fl4*)(in + (size_t)(r0 + r) * C + c0 + cg);
    tile[r * 33 + cg] = v[0]; tile[r * 33 + cg + 1] = v[1];
    tile[r * 33 + cg + 2] = v[2]; tile[r * 33 + cg + 3] = v[3];
  }
  __syncthreads();
  {
    const int cc = t >> 3, rg = (t & 7) * 4;
    u32x2 p;
    p[0] = pk2u(tile[(rg + 0) * 33 + cc], tile[(rg + 1) * 33 + cc]);
    p[1] = pk2u(tile[(rg + 2) * 33 + cc], tile[(rg + 3) * 33 + cc]);
    *(u32x2*)(out + (size_t)(c0 + cc) * R + r0 + rg) = p;
  }
}

__global__ __launch_bounds__(256) void prep(
    const float* __restrict__ X, __fp16* __restrict__ Xf,
    __fp16* __restrict__ XT,
    const float* __restrict__ Wq, const float* __restrict__ Wk,
    const float* __restrict__ Wv, __fp16* __restrict__ WqT,
    __fp16* __restrict__ WkT, __fp16* __restrict__ WvT,
    const float* __restrict__ pk, const float* __restrict__ pv,
    __fp16* __restrict__ pkT, __fp16* __restrict__ pvT) {
  __shared__ float tile[32 * 65];
  const int id = blockIdx.x;
  const int t = threadIdx.x;
  if (id < 8192) {
    // xprep: 32n x 64d tile
    const int n0 = (id & 127) * 32, d0 = ((id >> 7) & 15) * 64, b = id >> 11;
    const float* src = X + ((size_t)b * 4096 + n0) * 1024 + d0;
    {
      const int r = t >> 3, cg = (t & 7) * 8;
      fl4 v0 = *(const fl4*)(src + (size_t)r * 1024 + cg);
      fl4 v1 = *(const fl4*)(src + (size_t)r * 1024 + cg + 4);
      *(f16x8*)(Xf + ((size_t)b * 4096 + n0 + r) * 1024 + d0 + cg) = pk8(v0, v1);
#pragma unroll
      for (int j = 0; j < 4; ++j) {
        tile[r * 65 + cg + j] = v0[j];
        tile[r * 65 + cg + 4 + j] = v1[j];
      }
    }
    __syncthreads();
    {
      const int d = t >> 2, ng = (t & 3) * 8;
      fl4 a, c;
#pragma unroll
      for (int j = 0; j < 4; ++j) {
        a[j] = tile[(ng + j) * 65 + d];
        c[j] = tile[(ng + 4 + j) * 65 + d];
      }
      *(f16x8*)(XT + ((size_t)b * 1024 + d0 + d) * 4096 + n0 + ng) = pk8(a, c);
    }
  } else if (id < 11264) {
    const int idx = id - 8192;
    const int z = idx >> 10;
    const float* in = (z == 0) ? Wq : (z == 1) ? Wk : Wv;
    __fp16* out = (z == 0) ? WqT : (z == 1) ? WkT : WvT;
    tr_cvt_body(tile, in, out, 1024, 1024, idx & 31, (idx >> 5) & 31);
  } else {
    const int idx = id - 11264;
    const int z = idx >> 10;
    tr_cvt_body(tile, z ? pv : pk, z ? pvT : pkT, 4096, 256, idx & 7,
                (idx >> 3) & 127);
  }
}

// ---------------------------------------------------------------------------
// Stage 1 (r12 + f16 partials): Pk16[z][kk][dd] = sum_{n chunk c}
// pkT[kk][n]*XT[b][dd][n], z = c*4+b. 64kk x 64dd, BK=64, 16 iters.
// ---------------------------------------------------------------------------
__global__ __launch_bounds__(256) void stage1_partial(
    const __fp16* __restrict__ pkT,  // [256][4096]
    const __fp16* __restrict__ pvT,  // [256][4096]
    const __fp16* __restrict__ XT,   // [b][1024][4096]
    __fp16* __restrict__ Pk,         // [16][256][1024] f16 partials
    __fp16* __restrict__ Pv) {       // [16][256][1024]
  __shared__ __fp16 Ak[64 * 64];
  __shared__ __fp16 Av[64 * 64];
  __shared__ __fp16 Bx[64 * 64];
  const int t = threadIdx.x;
  const int lane = t & 63, w = t >> 6;
  const int lr = lane & 15, lg = lane >> 4;
  const int fid = blockIdx.x;
  const int g = fid >> 5, s5 = fid & 31;
  const int kk0 = (s5 >> 3) * 64, p8 = s5 & 7;
  const int pr = g * 8 + p8;
  const int dd0 = (pr & 15) * 64;
  const int z = pr >> 4, b = z & 3, c = z >> 2;
  const int wr = (w >> 1) * 32, wc = (w & 1) * 32;

  f32x4 acck[2][2], accv[2][2];
#pragma unroll
  for (int i = 0; i < 2; ++i)
#pragma unroll
    for (int j = 0; j < 2; ++j) {
      acck[i][j] = (f32x4){0.f, 0.f, 0.f, 0.f};
      accv[i][j] = (f32x4){0.f, 0.f, 0.f, 0.f};
    }

  const int r8 = lane >> 3, c8 = lane & 7;
  const int ssw = ((c8 ^ r8) * 8);
  const __fp16* pkS0 = pkT + (size_t)(kk0 + w * 8 + r8) * 4096 + c * 1024 + ssw;
  const __fp16* pkS1 = pkS0 + (size_t)32 * 4096;
  const __fp16* pvS0 = pvT + (size_t)(kk0 + w * 8 + r8) * 4096 + c * 1024 + ssw;
  const __fp16* pvS1 = pvS0 + (size_t)32 * 4096;
  const __fp16* xS0 =
      XT + ((size_t)b * 1024 + dd0 + w * 8 + r8) * 4096 + c * 1024 + ssw;
  const __fp16* xS1 = xS0 + (size_t)32 * 4096;

  for (int it = 0; it < 16; ++it) {
    const int n0 = it * 64;
    __syncthreads();
    gload_lds16(pkS0 + n0, (char*)Ak + w * 1024);
    gload_lds16(pkS1 + n0, (char*)Ak + 4096 + w * 1024);
    gload_lds16(pvS0 + n0, (char*)Av + w * 1024);
    gload_lds16(pvS1 + n0, (char*)Av + 4096 + w * 1024);
    gload_lds16(xS0 + n0, (char*)Bx + w * 1024);
    gload_lds16(xS1 + n0, (char*)Bx + 4096 + w * 1024);
    __syncthreads();

#pragma unroll
    for (int s = 0; s < 2; ++s) {
      f16x8 ak[2], av[2], bx[2];
#pragma unroll
      for (int i = 0; i < 2; ++i) {
        ak[i] = rd128(Ak, wr + i * 16 + lr, s * 4 + lg);
        av[i] = rd128(Av, wr + i * 16 + lr, s * 4 + lg);
      }
#pragma unroll
      for (int j = 0; j < 2; ++j)
        bx[j] = rd128(Bx, wc + j * 16 + lr, s * 4 + lg);
#pragma unroll
      for (int i = 0; i < 2; ++i)
#pragma unroll
        for (int j = 0; j < 2; ++j) {
          acck[i][j] = MFMA16(ak[i], bx[j], acck[i][j]);
          accv[i][j] = MFMA16(av[i], bx[j], accv[i][j]);
        }
    }
  }

#pragma unroll
  for (int i = 0; i < 2; ++i)
#pragma unroll
    for (int j = 0; j < 2; ++j)
#pragma unroll
      for (int r = 0; r < 4; ++r) {
        const size_t row = (size_t)z * 256 + kk0 + wr + i * 16 + lg * 4 + r;
        const int col = dd0 + wc + j * 16 + lr;
        Pk[row * 1024 + col] = (__fp16)acck[i][j][r];
        Pv[row * 1024 + col] = (__fp16)accv[i][j][r];
      }
}

// ---------------------------------------------------------------------------
// Stage 1 reduce (f16 in, f32 accum): Xk = f16(sum_c Pk16[c*4+b]).
// ---------------------------------------------------------------------------
__global__ __launch_bounds__(256) void stage1_reduce(
    const __fp16* __restrict__ Pk, const __fp16* __restrict__ Pv,
    __fp16* __restrict__ Xk, __fp16* __restrict__ Xv) {
  const size_t idx = ((size_t)blockIdx.x * 256 + threadIdx.x) * 8;
  const int b = (int)(idx >> 18);           // 262144 elems per batch slab
  const size_t rem = idx & 0x3FFFFu;
  float sk[8], sv[8];
#pragma unroll
  for (int j = 0; j < 8; ++j) { sk[j] = 0.f; sv[j] = 0.f; }
#pragma unroll
  for (int c = 0; c < 4; ++c) {
    const size_t off = (((size_t)(c * 4 + b)) << 18) + rem;
    f16x8 vk = *(const f16x8*)(Pk + off);
    f16x8 vv = *(const f16x8*)(Pv + off);
#pragma unroll
    for (int j = 0; j < 8; ++j) {
      sk[j] += (float)vk[j];
      sv[j] += (float)vv[j];
    }
  }
  f16x8 ok, ov;
#pragma unroll
  for (int j = 0; j < 8; ++j) {
    ok[j] = (__fp16)sk[j];
    ov[j] = (__fp16)sv[j];
  }
  *(f16x8*)(Xk + idx) = ok;
  *(f16x8*)(Xv + idx) = ov;
}

// ---------------------------------------------------------------------------
// bt64z: both small BT-GEMMs in one launch (512 blocks).
// id<256: Kp[z][i][j] = sum_e Xk[z][i][e]*WkT[j][e]   (grid 4x16x4)
// id>=256: Vpt[z][i][j] = sum_e WvT[i][e]*Xv[z][j][e] (grid 16x4x4)
// 64x64 tile, BK=64 (16 iters), stage1-style gload staging.
// ---------------------------------------------------------------------------
__global__ __launch_bounds__(256) void bt64z(
    const __fp16* __restrict__ Xk, const __fp16* __restrict__ WkT,
    __fp16* __restrict__ Kp, const __fp16* __restrict__ WvT,
    const __fp16* __restrict__ Xv, __fp16* __restrict__ Vpt) {
  constexpr int E = 1024;
  __shared__ __fp16 As[64 * 64];
  __shared__ __fp16 Bs[64 * 64];
  const int t = threadIdx.x;
  const int lane = t & 63, w = t >> 6;
  const int lr = lane & 15, lg = lane >> 4;
  int id = blockIdx.x;
  const __fp16 *A, *B;
  __fp16* C;
  int i0, j0, ldC;
  if (id < 256) {
    const int x = id & 3, y = (id >> 2) & 15, z = id >> 6;
    A = Xk + (size_t)z * 256 * 1024; B = WkT;
    C = Kp + (size_t)z * 256 * 1024;
    i0 = x * 64; j0 = y * 64; ldC = 1024;
  } else {
    id -= 256;
    const int x = id & 15, y = (id >> 4) & 3, z = id >> 6;
    A = WvT; B = Xv + (size_t)z * 256 * 1024;
    C = Vpt + (size_t)z * 1024 * 256;
    i0 = x * 64; j0 = y * 64; ldC = 256;
  }
  const int wr = (w >> 1) * 32, wc = (w & 1) * 32;

  f32x4 acc[2][2];
#pragma unroll
  for (int i = 0; i < 2; ++i)
#pragma unroll
    for (int j = 0; j < 2; ++j) acc[i][j] = (f32x4){0.f, 0.f, 0.f, 0.f};

  const int r8 = lane >> 3, c8 = lane & 7;
  const int ssw = ((c8 ^ r8) * 8);
  const __fp16* aS0 = A + (size_t)(i0 + w * 8 + r8) * E + ssw;
  const __fp16* aS1 = aS0 + (size_t)32 * E;
  const __fp16* bS0 = B + (size_t)(j0 + w * 8 + r8) * E + ssw;
  const __fp16* bS1 = bS0 + (size_t)32 * E;

  for (int it = 0; it < 16; ++it) {
    const int e0 = it * 64;
    __syncthreads();
    gload_lds16(aS0 + e0, (char*)As + w * 1024);
    gload_lds16(aS1 + e0, (char*)As + 4096 + w * 1024);
    gload_lds16(bS0 + e0, (char*)Bs + w * 1024);
    gload_lds16(bS1 + e0, (char*)Bs + 4096 + w * 1024);
    __syncthreads();

#pragma unroll
    for (int s = 0; s < 2; ++s) {
      f16x8 af[2], bf[2];
#pragma unroll
      for (int i = 0; i < 2; ++i)
        af[i] = rd128(As, wr + i * 16 + lr, s * 4 + lg);
#pragma unroll
      for (int j = 0; j < 2; ++j)
        bf[j] = rd128(Bs, wc + j * 16 + lr, s * 4 + lg);
#pragma unroll
      for (int i = 0; i < 2; ++i)
#pragma unroll
        for (int j = 0; j < 2; ++j)
          acc[i][j] = MFMA16(af[i], bf[j], acc[i][j]);
    }
  }

#pragma unroll
  for (int i = 0; i < 2; ++i)
#pragma unroll
    for (int j = 0; j < 2; ++j)
#pragma unroll
      for (int r = 0; r < 4; ++r) {
        const int row = i0 + wr + i * 16 + lg * 4 + r;
        const int col = j0 + wc + j * 16 + lr;
        C[(size_t)row * ldC + col] = (__fp16)acc[i][j][r];
      }
}

// ---------------------------------------------------------------------------
// Q-path GEMM (r12): Qh = Xf16 . WqT^T, 128x128, BK=64, 16 iters, pure
// gload_lds, single buffer. XCD swizzle: fid = g*64 + n*8 + p.
// ---------------------------------------------------------------------------
__global__ __launch_bounds__(256) void gemm_q(
    const __fp16* __restrict__ Xf,   // [16384][1024] f16
    const __fp16* __restrict__ WT,   // [1024][1024], WT[n][k] = W[k][n]
    __fp16* __restrict__ Q) {
  constexpr int K = 1024, N = 1024;
  __shared__ __fp16 Xs[128 * 64];  // 16KB
  __shared__ __fp16 Ws[128 * 64];
  const int t = threadIdx.x;
  const int lane = t & 63, w = t >> 6;
  const int lr = lane & 15, lg = lane >> 4;
  const int fid = blockIdx.x;
  const int g = fid >> 6, s6 = fid & 63;
  const int n0 = (s6 >> 3) * 128;
  const int m0 = (g * 8 + (s6 & 7)) * 128;
  const int wr = (w >> 1) * 64, wc = (w & 1) * 64;

  f32x4 acc[4][4];
#pragma unroll
  for (int i = 0; i < 4; ++i)
#pragma unroll
    for (int j = 0; j < 4; ++j) acc[i][j] = (f32x4){0.f, 0.f, 0.f, 0.f};

  const int r8 = lane >> 3, c8 = lane & 7;
  const int ssw = ((c8 ^ r8) * 8);
  const __fp16* xS = Xf + (size_t)(m0 + w * 8 + r8) * K + ssw;
  const __fp16* wS = WT + (size_t)(n0 + w * 8 + r8) * K + ssw;

  for (int it = 0; it < 16; ++it) {
    const int k0 = it * 64;
    __syncthreads();
#pragma unroll
    for (int i = 0; i < 4; ++i) {
      gload_lds16(xS + (size_t)i * 32 * K + k0, (char*)Xs + i * 4096 + w * 1024);
      gload_lds16(wS + (size_t)i * 32 * K + k0, (char*)Ws + i * 4096 + w * 1024);
    }
    __syncthreads();

#pragma unroll
    for (int s = 0; s < 2; ++s) {
      f16x8 af[4], bf[4];
#pragma unroll
      for (int i = 0; i < 4; ++i)
        af[i] = rd128(Xs, wr + i * 16 + lr, s * 4 + lg);
#pragma unroll
      for (int j = 0; j < 4; ++j)
        bf[j] = rd128(Ws, wc + j * 16 + lr, s * 4 + lg);
#pragma unroll
      for (int i = 0; i < 4; ++i)
#pragma unroll
        for (int j = 0; j < 4; ++j)
          acc[i][j] = MFMA16(af[i], bf[j], acc[i][j]);
    }
  }

#pragma unroll
  for (int i = 0; i < 4; ++i)
#pragma unroll
    for (int j = 0; j < 4; ++j)
#pragma unroll
      for (int r = 0; r < 4; ++r) {
        const int row = m0 + wr + i * 16 + lg * 4 + r;
        const int col = n0 + wc + j * 16 + lr;
        Q[(size_t)row * N + col] = (__fp16)acc[i][j][r];
      }
}

// ---------------------------------------------------------------------------
// Attention v3 (verified r8-r12): block = 4 waves, 128 Q-rows of one (b,h);
// grid 2048. 32KB LDS (K then V), swapped QK^T, in-register P via
// cvt_pk + ds_bpermute.
// ---------------------------------------------------------------------------
__global__ __launch_bounds__(256) void attn_k(
    const __fp16* __restrict__ Q,    // [b*4096][1024]
    const __fp16* __restrict__ Kp,   // [b][256][1024]
    const __fp16* __restrict__ Vpt,  // [b][1024][256]
    float* __restrict__ O) {         // [b*4096][1024] f32
  __shared__ __fp16 KV[256 * 64];    // 32KB: K tile, then V^T tile
  const int t = threadIdx.x;
  const int lane = t & 63, w = t >> 6;
  const int lr = lane & 15, lg = lane >> 4;
  const int bh = blockIdx.x >> 5, rb = blockIdx.x & 31;
  const int b = bh >> 4, h = bh & 15;
  const int m0 = rb * 128 + w * 32;

  const __fp16* Kph = Kp + (size_t)b * 256 * 1024 + h * 64;
  const __fp16* Vph = Vpt + ((size_t)b * 1024 + h * 64) * 256;
  const __fp16* Qh = Q + ((size_t)(b * 4096 + m0)) * 1024 + h * 64;

#pragma unroll
  for (int i = 0; i < 8; ++i) {
    const int kr = (i * 4 + w) * 8 + (lane >> 3);
    gload_lds16(Kph + (size_t)kr * 1024 + (((lane & 7) ^ (kr & 7)) * 8),
                (char*)KV + (i * 4 + w) * 1024);
  }

  f16x8 aq[2][2];
#pragma unroll
  for (int mi = 0; mi < 2; ++mi)
#pragma unroll
    for (int s = 0; s < 2; ++s)
      aq[mi][s] =
          *(const f16x8*)(Qh + (size_t)(mi * 16 + lr) * 1024 + s * 32 + lg * 8);

  __syncthreads();  // K staged

  f32x4 dots[2][16];
#pragma unroll
  for (int mi = 0; mi < 2; ++mi)
#pragma unroll
    for (int jt = 0; jt < 16; ++jt) dots[mi][jt] = (f32x4){0.f, 0.f, 0.f, 0.f};
#pragma unroll
  for (int jt = 0; jt < 16; ++jt) {
    const int r = jt * 16 + lr;
    f16x8 k0 = *(const f16x8*)((const char*)KV + r * 128 + ((lg ^ (r & 7)) * 16));
    f16x8 k1 =
        *(const f16x8*)((const char*)KV + r * 128 + (((4 + lg) ^ (r & 7)) * 16));
    dots[0][jt] = MFMA16(k0, aq[0][0], dots[0][jt]);
    dots[0][jt] = MFMA16(k1, aq[0][1], dots[0][jt]);
    dots[1][jt] = MFMA16(k0, aq[1][0], dots[1][jt]);
    dots[1][jt] = MFMA16(k1, aq[1][1], dots[1][jt]);
  }

  unsigned cpk[2][16][2];
  float smv[2];
#pragma unroll
  for (int mi = 0; mi < 2; ++mi) {
    float mx = -1e30f;
#pragma unroll
    for (int jt = 0; jt < 16; ++jt)
#pragma unroll
      for (int r = 0; r < 4; ++r) mx = fmaxf(mx, dots[mi][jt][r]);
    mx = fmaxf(mx, __shfl_xor(mx, 16, 64));
    mx = fmaxf(mx, __shfl_xor(mx, 32, 64));
    float sm = 0.f;
#pragma unroll
    for (int jt = 0; jt < 16; ++jt) {
#pragma unroll
      for (int r = 0; r < 4; ++r) {
        float p = __expf(dots[mi][jt][r] - mx);
        dots[mi][jt][r] = p;
        sm += p;
      }
      cpk[mi][jt][0] = pk2u(dots[mi][jt][0], dots[mi][jt][1]);
      cpk[mi][jt][1] = pk2u(dots[mi][jt][2], dots[mi][jt][3]);
    }
    sm += __shfl_xor(sm, 16, 64);
    sm += __shfl_xor(sm, 32, 64);
    smv[mi] = sm;
  }

  __syncthreads();  // all waves done reading K

#pragma unroll
  for (int i = 0; i < 8; ++i) {
    const int dd = (i * 4 + w) * 2 + (lane >> 5);
    gload_lds16(Vph + (size_t)dd * 256 + (((lane & 31) ^ (dd & 7)) * 8),
                (char*)KV + (i * 4 + w) * 1024);
  }
  __syncthreads();  // V staged

#pragma unroll
  for (int mi = 0; mi < 2; ++mi) {
    f32x4 o[4];
#pragma unroll
    for (int j = 0; j < 4; ++j) o[j] = (f32x4){0.f, 0.f, 0.f, 0.f};
#pragma unroll
    for (int ks = 0; ks < 8; ++ks) {
      u32x4 wds;
#pragma unroll
      for (int m = 0; m < 4; ++m) {
        const int addr = ((((lane & 16) >> 3) + (m >> 1)) * 16 + lr) * 4;
        const int a0 = __builtin_amdgcn_ds_bpermute(
            addr, (int)cpk[mi][ks * 2][m & 1]);
        const int a1 = __builtin_amdgcn_ds_bpermute(
            addr, (int)cpk[mi][ks * 2 + 1][m & 1]);
        wds[m] = (unsigned)((lg >> 1) ? a1 : a0);
      }
      f16x8 pa = __builtin_bit_cast(f16x8, wds);
#pragma unroll
      for (int jt2 = 0; jt2 < 4; ++jt2) {
        const int dd = jt2 * 16 + lr;
        f16x8 bv = *(const f16x8*)((const char*)KV + dd * 512 +
                                   (((ks * 4 + lg) ^ (dd & 7)) * 16));
        o[jt2] = MFMA16(pa, bv, o[jt2]);
      }
    }

    float rs[4];
#pragma unroll
    for (int r = 0; r < 4; ++r)
      rs[r] = 1.f / __shfl(smv[mi], (lane & 48) + lg * 4 + r, 64);
#pragma unroll
    for (int jt2 = 0; jt2 < 4; ++jt2)
#pragma unroll
      for (int r = 0; r < 4; ++r) {
        const size_t row = (size_t)(b * 4096 + m0 + mi * 16 + lg * 4 + r);
        O[row * 1024 + h * 64 + jt2 * 16 + lr] = o[jt2][r] * rs[r];
      }
  }
}

// ---------------------------------------------------------------------------
extern "C" void kernel_launch(void* const* d_in, const int* in_sizes, int n_in,
                              void* d_out, int out_size, void* d_ws, size_t ws_size,
                              hipStream_t stream) {
  (void)in_sizes; (void)n_in; (void)out_size; (void)ws_size;
  const float* x  = (const float*)d_in[0];
  const float* Wq = (const float*)d_in[1];
  const float* Wk = (const float*)d_in[2];
  const float* Wv = (const float*)d_in[3];
  const float* pk = (const float*)d_in[4];
  const float* pv = (const float*)d_in[5];
  float* out = (float*)d_out;

  // ws layout (f16), ~52.4 MB. Qh region doubles as f16 partials (16.8 MB)
  // for stage1; gemm_q overwrites it after the reduce. Xf16 + XT (33.5 MB
  // each) live in d_out, fully overwritten by attn_k at the end.
  __fp16* Qh  = (__fp16*)d_ws;                       // 16384*1024 f16
  __fp16* WqT = Qh  + (size_t)16384 * 1024;          // 1024*1024 each
  __fp16* WkT = WqT + (size_t)1024 * 1024;
  __fp16* WvT = WkT + (size_t)1024 * 1024;
  __fp16* pkT = WvT + (size_t)1024 * 1024;           // 256*4096 each
  __fp16* pvT = pkT + (size_t)256 * 4096;
  __fp16* Xk  = pvT + (size_t)256 * 4096;            // 4*256*1024 each
  __fp16* Xv  = Xk  + (size_t)4 * 256 * 1024;
  __fp16* Kp  = Xv  + (size_t)4 * 256 * 1024;
  __fp16* Vpt = Kp  + (size_t)4 * 256 * 1024;
  __fp16* Pk16 = (__fp16*)d_ws;                      // 16*256*1024 f16 each
  __fp16* Pv16 = Pk16 + (size_t)16 * 256 * 1024;
  __fp16* Xf16 = (__fp16*)d_out;                     // 4*4096*1024 f16
  __fp16* XT   = Xf16 + (size_t)4 * 4096 * 1024;     // 4*1024*4096 f16

  const dim3 bb(256);

  // 0. all conversions in one launch
  prep<<<dim3(13312), bb, 0, stream>>>(x, Xf16, XT, Wq, Wk, Wv, WqT, WkT, WvT,
                                       pk, pv, pkT, pvT);

  // 1. split-K low-rank projections of X^T + reduce (f16 partials)
  stage1_partial<<<dim3(1024), bb, 0, stream>>>(pkT, pvT, XT, Pk16, Pv16);
  stage1_reduce<<<dim3(512), bb, 0, stream>>>(Pk16, Pv16, Xk, Xv);

  // 2. Kp = Xk . Wk ; VpT = (Xv . Wv)^T  (single launch, BK=64)
  bt64z<<<dim3(512), bb, 0, stream>>>(Xk, WkT, Kp, WvT, Xv, Vpt);

  // 3. Q projection (r12 form; overwrites partials region)
  gemm_q<<<dim3(1024), bb, 0, stream>>>(Xf16, WqT, Qh);

  // 4. attention (overwrites Xf16/XT = d_out)
  attn_k<<<dim3(2048), bb, 0, stream>>>(Qh, Kp, Vpt, out);
}

// Round 17
// 155.761 us; speedup vs baseline: 1.5961x; 1.0701x over previous
//
#include <hip/hip_runtime.h>

// ---------------------------------------------------------------------------
// Linformer self-attention, fp32 I/O, fp16 MFMA internally, MI355X (gfx950)
// b=4 n=4096 d=1024 h=16 dh=64 k=256  (no 1/sqrt(dh) scale per reference)
//
// Round 17: r16 (best, 166.7) with gemm_q widened to a 256x128 tile,
// 8 waves / 512 threads, BK=64 — halves barrier-drains per output FLOP.
// Same verified staging/swizzle algebra. Everything else unchanged.
// ---------------------------------------------------------------------------

typedef __fp16 f16x8 __attribute__((ext_vector_type(8)));
typedef __fp16 f16x2 __attribute__((ext_vector_type(2)));
typedef float fl4 __attribute__((ext_vector_type(4)));
typedef float f32x4 __attribute__((ext_vector_type(4)));
typedef unsigned int u32x2 __attribute__((ext_vector_type(2)));
typedef unsigned int u32x4 __attribute__((ext_vector_type(4)));

#define MFMA16(a, b, c) __builtin_amdgcn_mfma_f32_16x16x32_f16((a), (b), (c), 0, 0, 0)

__device__ __forceinline__ unsigned int pk2u(float a, float b) {
  f16x2 p = __builtin_amdgcn_cvt_pkrtz(a, b);  // low = a, high = b
  return __builtin_bit_cast(unsigned int, p);
}

__device__ __forceinline__ f16x8 pk8(fl4 a, fl4 b) {
  f16x2 p0 = __builtin_amdgcn_cvt_pkrtz(a[0], a[1]);
  f16x2 p1 = __builtin_amdgcn_cvt_pkrtz(a[2], a[3]);
  f16x2 p2 = __builtin_amdgcn_cvt_pkrtz(b[0], b[1]);
  f16x2 p3 = __builtin_amdgcn_cvt_pkrtz(b[2], b[3]);
  f16x8 r;
  r[0] = p0[0]; r[1] = p0[1]; r[2] = p1[0]; r[3] = p1[1];
  r[4] = p2[0]; r[5] = p2[1]; r[6] = p3[0]; r[7] = p3[1];
  return r;
}

__device__ __forceinline__ void gload_lds16(const __fp16* g, void* lds_base) {
  __builtin_amdgcn_global_load_lds(
      (const __attribute__((address_space(1))) void*)g,
      (__attribute__((address_space(3))) void*)lds_base, 16, 0, 0);
}

// 128B-row tile fragment read: logical 16B chunk `ch` of `row`
__device__ __forceinline__ f16x8 rd128(const __fp16* base, int row, int ch) {
  return *(const f16x8*)((const char*)base + row * 128 +
                         ((ch ^ (row & 7)) * 16));
}

// ---------------------------------------------------------------------------
// prep: one launch. Blocks [0,8192): xprep (X f32 -> Xf16 + XT f16).
// [8192,11264): 3x W 1024x1024 transpose+cvt. [11264,13312): 2x proj
// 4096x256 transpose+cvt.
// ---------------------------------------------------------------------------
__device__ __forceinline__ void tr_cvt_body(
    float* tile, const float* in, __fp16* out, int R, int C, int bx, int by) {
  const int t = threadIdx.x;
  const int c0 = bx * 32, r0 = by * 32;
  {
    const int r = t >> 3, cg = (t & 7) * 4;
    fl4 v = *(const fl4*)(in + (size_t)(r0 + r) * C + c0 + cg);
    tile[r * 33 + cg] = v[0]; tile[r * 33 + cg + 1] = v[1];
    tile[r * 33 + cg + 2] = v[2]; tile[r * 33 + cg + 3] = v[3];
  }
  __syncthreads();
  {
    const int cc = t >> 3, rg = (t & 7) * 4;
    u32x2 p;
    p[0] = pk2u(tile[(rg + 0) * 33 + cc], tile[(rg + 1) * 33 + cc]);
    p[1] = pk2u(tile[(rg + 2) * 33 + cc], tile[(rg + 3) * 33 + cc]);
    *(u32x2*)(out + (size_t)(c0 + cc) * R + r0 + rg) = p;
  }
}

__global__ __launch_bounds__(256) void prep(
    const float* __restrict__ X, __fp16* __restrict__ Xf,
    __fp16* __restrict__ XT,
    const float* __restrict__ Wq, const float* __restrict__ Wk,
    const float* __restrict__ Wv, __fp16* __restrict__ WqT,
    __fp16* __restrict__ WkT, __fp16* __restrict__ WvT,
    const float* __restrict__ pk, const float* __restrict__ pv,
    __fp16* __restrict__ pkT, __fp16* __restrict__ pvT) {
  __shared__ float tile[32 * 65];
  const int id = blockIdx.x;
  const int t = threadIdx.x;
  if (id < 8192) {
    // xprep: 32n x 64d tile
    const int n0 = (id & 127) * 32, d0 = ((id >> 7) & 15) * 64, b = id >> 11;
    const float* src = X + ((size_t)b * 4096 + n0) * 1024 + d0;
    {
      const int r = t >> 3, cg = (t & 7) * 8;
      fl4 v0 = *(const fl4*)(src + (size_t)r * 1024 + cg);
      fl4 v1 = *(const fl4*)(src + (size_t)r * 1024 + cg + 4);
      *(f16x8*)(Xf + ((size_t)b * 4096 + n0 + r) * 1024 + d0 + cg) = pk8(v0, v1);
#pragma unroll
      for (int j = 0; j < 4; ++j) {
        tile[r * 65 + cg + j] = v0[j];
        tile[r * 65 + cg + 4 + j] = v1[j];
      }
    }
    __syncthreads();
    {
      const int d = t >> 2, ng = (t & 3) * 8;
      fl4 a, c;
#pragma unroll
      for (int j = 0; j < 4; ++j) {
        a[j] = tile[(ng + j) * 65 + d];
        c[j] = tile[(ng + 4 + j) * 65 + d];
      }
      *(f16x8*)(XT + ((size_t)b * 1024 + d0 + d) * 4096 + n0 + ng) = pk8(a, c);
    }
  } else if (id < 11264) {
    const int idx = id - 8192;
    const int z = idx >> 10;
    const float* in = (z == 0) ? Wq : (z == 1) ? Wk : Wv;
    __fp16* out = (z == 0) ? WqT : (z == 1) ? WkT : WvT;
    tr_cvt_body(tile, in, out, 1024, 1024, idx & 31, (idx >> 5) & 31);
  } else {
    const int idx = id - 11264;
    const int z = idx >> 10;
    tr_cvt_body(tile, z ? pv : pk, z ? pvT : pkT, 4096, 256, idx & 7,
                (idx >> 3) & 127);
  }
}

// ---------------------------------------------------------------------------
// Stage 1 (r12 + f16 partials): Pk16[z][kk][dd] = sum_{n chunk c}
// pkT[kk][n]*XT[b][dd][n], z = c*4+b. 64kk x 64dd, BK=64, 16 iters.
// ---------------------------------------------------------------------------
__global__ __launch_bounds__(256) void stage1_partial(
    const __fp16* __restrict__ pkT,  // [256][4096]
    const __fp16* __restrict__ pvT,  // [256][4096]
    const __fp16* __restrict__ XT,   // [b][1024][4096]
    __fp16* __restrict__ Pk,         // [16][256][1024] f16 partials
    __fp16* __restrict__ Pv) {       // [16][256][1024]
  __shared__ __fp16 Ak[64 * 64];
  __shared__ __fp16 Av[64 * 64];
  __shared__ __fp16 Bx[64 * 64];
  const int t = threadIdx.x;
  const int lane = t & 63, w = t >> 6;
  const int lr = lane & 15, lg = lane >> 4;
  const int fid = blockIdx.x;
  const int g = fid >> 5, s5 = fid & 31;
  const int kk0 = (s5 >> 3) * 64, p8 = s5 & 7;
  const int pr = g * 8 + p8;
  const int dd0 = (pr & 15) * 64;
  const int z = pr >> 4, b = z & 3, c = z >> 2;
  const int wr = (w >> 1) * 32, wc = (w & 1) * 32;

  f32x4 acck[2][2], accv[2][2];
#pragma unroll
  for (int i = 0; i < 2; ++i)
#pragma unroll
    for (int j = 0; j < 2; ++j) {
      acck[i][j] = (f32x4){0.f, 0.f, 0.f, 0.f};
      accv[i][j] = (f32x4){0.f, 0.f, 0.f, 0.f};
    }

  const int r8 = lane >> 3, c8 = lane & 7;
  const int ssw = ((c8 ^ r8) * 8);
  const __fp16* pkS0 = pkT + (size_t)(kk0 + w * 8 + r8) * 4096 + c * 1024 + ssw;
  const __fp16* pkS1 = pkS0 + (size_t)32 * 4096;
  const __fp16* pvS0 = pvT + (size_t)(kk0 + w * 8 + r8) * 4096 + c * 1024 + ssw;
  const __fp16* pvS1 = pvS0 + (size_t)32 * 4096;
  const __fp16* xS0 =
      XT + ((size_t)b * 1024 + dd0 + w * 8 + r8) * 4096 + c * 1024 + ssw;
  const __fp16* xS1 = xS0 + (size_t)32 * 4096;

  for (int it = 0; it < 16; ++it) {
    const int n0 = it * 64;
    __syncthreads();
    gload_lds16(pkS0 + n0, (char*)Ak + w * 1024);
    gload_lds16(pkS1 + n0, (char*)Ak + 4096 + w * 1024);
    gload_lds16(pvS0 + n0, (char*)Av + w * 1024);
    gload_lds16(pvS1 + n0, (char*)Av + 4096 + w * 1024);
    gload_lds16(xS0 + n0, (char*)Bx + w * 1024);
    gload_lds16(xS1 + n0, (char*)Bx + 4096 + w * 1024);
    __syncthreads();

#pragma unroll
    for (int s = 0; s < 2; ++s) {
      f16x8 ak[2], av[2], bx[2];
#pragma unroll
      for (int i = 0; i < 2; ++i) {
        ak[i] = rd128(Ak, wr + i * 16 + lr, s * 4 + lg);
        av[i] = rd128(Av, wr + i * 16 + lr, s * 4 + lg);
      }
#pragma unroll
      for (int j = 0; j < 2; ++j)
        bx[j] = rd128(Bx, wc + j * 16 + lr, s * 4 + lg);
#pragma unroll
      for (int i = 0; i < 2; ++i)
#pragma unroll
        for (int j = 0; j < 2; ++j) {
          acck[i][j] = MFMA16(ak[i], bx[j], acck[i][j]);
          accv[i][j] = MFMA16(av[i], bx[j], accv[i][j]);
        }
    }
  }

#pragma unroll
  for (int i = 0; i < 2; ++i)
#pragma unroll
    for (int j = 0; j < 2; ++j)
#pragma unroll
      for (int r = 0; r < 4; ++r) {
        const size_t row = (size_t)z * 256 + kk0 + wr + i * 16 + lg * 4 + r;
        const int col = dd0 + wc + j * 16 + lr;
        Pk[row * 1024 + col] = (__fp16)acck[i][j][r];
        Pv[row * 1024 + col] = (__fp16)accv[i][j][r];
      }
}

// ---------------------------------------------------------------------------
// Stage 1 reduce (f16 in, f32 accum): Xk = f16(sum_c Pk16[c*4+b]).
// ---------------------------------------------------------------------------
__global__ __launch_bounds__(256) void stage1_reduce(
    const __fp16* __restrict__ Pk, const __fp16* __restrict__ Pv,
    __fp16* __restrict__ Xk, __fp16* __restrict__ Xv) {
  const size_t idx = ((size_t)blockIdx.x * 256 + threadIdx.x) * 8;
  const int b = (int)(idx >> 18);           // 262144 elems per batch slab
  const size_t rem = idx & 0x3FFFFu;
  float sk[8], sv[8];
#pragma unroll
  for (int j = 0; j < 8; ++j) { sk[j] = 0.f; sv[j] = 0.f; }
#pragma unroll
  for (int c = 0; c < 4; ++c) {
    const size_t off = (((size_t)(c * 4 + b)) << 18) + rem;
    f16x8 vk = *(const f16x8*)(Pk + off);
    f16x8 vv = *(const f16x8*)(Pv + off);
#pragma unroll
    for (int j = 0; j < 8; ++j) {
      sk[j] += (float)vk[j];
      sv[j] += (float)vv[j];
    }
  }
  f16x8 ok, ov;
#pragma unroll
  for (int j = 0; j < 8; ++j) {
    ok[j] = (__fp16)sk[j];
    ov[j] = (__fp16)sv[j];
  }
  *(f16x8*)(Xk + idx) = ok;
  *(f16x8*)(Xv + idx) = ov;
}

// ---------------------------------------------------------------------------
// bt64z: both small BT-GEMMs in one launch (512 blocks).
// id<256: Kp[z][i][j] = sum_e Xk[z][i][e]*WkT[j][e]   (grid 4x16x4)
// id>=256: Vpt[z][i][j] = sum_e WvT[i][e]*Xv[z][j][e] (grid 16x4x4)
// 64x64 tile, BK=64 (16 iters), stage1-style gload staging.
// ---------------------------------------------------------------------------
__global__ __launch_bounds__(256) void bt64z(
    const __fp16* __restrict__ Xk, const __fp16* __restrict__ WkT,
    __fp16* __restrict__ Kp, const __fp16* __restrict__ WvT,
    const __fp16* __restrict__ Xv, __fp16* __restrict__ Vpt) {
  constexpr int E = 1024;
  __shared__ __fp16 As[64 * 64];
  __shared__ __fp16 Bs[64 * 64];
  const int t = threadIdx.x;
  const int lane = t & 63, w = t >> 6;
  const int lr = lane & 15, lg = lane >> 4;
  int id = blockIdx.x;
  const __fp16 *A, *B;
  __fp16* C;
  int i0, j0, ldC;
  if (id < 256) {
    const int x = id & 3, y = (id >> 2) & 15, z = id >> 6;
    A = Xk + (size_t)z * 256 * 1024; B = WkT;
    C = Kp + (size_t)z * 256 * 1024;
    i0 = x * 64; j0 = y * 64; ldC = 1024;
  } else {
    id -= 256;
    const int x = id & 15, y = (id >> 4) & 3, z = id >> 6;
    A = WvT; B = Xv + (size_t)z * 256 * 1024;
    C = Vpt + (size_t)z * 1024 * 256;
    i0 = x * 64; j0 = y * 64; ldC = 256;
  }
  const int wr = (w >> 1) * 32, wc = (w & 1) * 32;

  f32x4 acc[2][2];
#pragma unroll
  for (int i = 0; i < 2; ++i)
#pragma unroll
    for (int j = 0; j < 2; ++j) acc[i][j] = (f32x4){0.f, 0.f, 0.f, 0.f};

  const int r8 = lane >> 3, c8 = lane & 7;
  const int ssw = ((c8 ^ r8) * 8);
  const __fp16* aS0 = A + (size_t)(i0 + w * 8 + r8) * E + ssw;
  const __fp16* aS1 = aS0 + (size_t)32 * E;
  const __fp16* bS0 = B + (size_t)(j0 + w * 8 + r8) * E + ssw;
  const __fp16* bS1 = bS0 + (size_t)32 * E;

  for (int it = 0; it < 16; ++it) {
    const int e0 = it * 64;
    __syncthreads();
    gload_lds16(aS0 + e0, (char*)As + w * 1024);
    gload_lds16(aS1 + e0, (char*)As + 4096 + w * 1024);
    gload_lds16(bS0 + e0, (char*)Bs + w * 1024);
    gload_lds16(bS1 + e0, (char*)Bs + 4096 + w * 1024);
    __syncthreads();

#pragma unroll
    for (int s = 0; s < 2; ++s) {
      f16x8 af[2], bf[2];
#pragma unroll
      for (int i = 0; i < 2; ++i)
        af[i] = rd128(As, wr + i * 16 + lr, s * 4 + lg);
#pragma unroll
      for (int j = 0; j < 2; ++j)
        bf[j] = rd128(Bs, wc + j * 16 + lr, s * 4 + lg);
#pragma unroll
      for (int i = 0; i < 2; ++i)
#pragma unroll
        for (int j = 0; j < 2; ++j)
          acc[i][j] = MFMA16(af[i], bf[j], acc[i][j]);
    }
  }

#pragma unroll
  for (int i = 0; i < 2; ++i)
#pragma unroll
    for (int j = 0; j < 2; ++j)
#pragma unroll
      for (int r = 0; r < 4; ++r) {
        const int row = i0 + wr + i * 16 + lg * 4 + r;
        const int col = j0 + wc + j * 16 + lr;
        C[(size_t)row * ldC + col] = (__fp16)acc[i][j][r];
      }
}

// ---------------------------------------------------------------------------
// Q-path GEMM v5: 256x128 tile, 8 waves (512 threads), BK=64, 16 iters.
// Pure gload_lds both operands (A 32KB, B 16KB, 128B rows, src chunk c8^r8).
// Wave grid 4x2: wr = (w&3)*64, wc = (w>>2)*64; 4x4 frags per wave.
// XCD swizzle: fid = n_tile*64 + m_tile -> 8 n-blocks of one m-tile share XCD.
// ---------------------------------------------------------------------------
__global__ __launch_bounds__(512) void gemm_q(
    const __fp16* __restrict__ Xf,   // [16384][1024] f16
    const __fp16* __restrict__ WT,   // [1024][1024], WT[n][k] = W[k][n]
    __fp16* __restrict__ Q) {
  constexpr int K = 1024, N = 1024;
  __shared__ __fp16 Xs[256 * 64];  // 32KB
  __shared__ __fp16 Ws[128 * 64];  // 16KB
  const int t = threadIdx.x;
  const int lane = t & 63, w = t >> 6;        // w in [0,8)
  const int lr = lane & 15, lg = lane >> 4;
  const int fid = blockIdx.x;
  const int m0 = (fid & 63) * 256;
  const int n0 = (fid >> 6) * 128;
  const int wr = (w & 3) * 64, wc = (w >> 2) * 64;

  f32x4 acc[4][4];
#pragma unroll
  for (int i = 0; i < 4; ++i)
#pragma unroll
    for (int j = 0; j < 4; ++j) acc[i][j] = (f32x4){0.f, 0.f, 0.f, 0.f};

  const int r8 = lane >> 3, c8 = lane & 7;
  const int ssw = ((c8 ^ r8) * 8);
  const __fp16* xS = Xf + (size_t)(m0 + w * 8 + r8) * K + ssw;
  const __fp16* wS = WT + (size_t)(n0 + w * 8 + r8) * K + ssw;

  for (int it = 0; it < 16; ++it) {
    const int k0 = it * 64;
    __syncthreads();
#pragma unroll
    for (int i = 0; i < 4; ++i)
      gload_lds16(xS + (size_t)i * 64 * K + k0, (char*)Xs + i * 8192 + w * 1024);
#pragma unroll
    for (int i = 0; i < 2; ++i)
      gload_lds16(wS + (size_t)i * 64 * K + k0, (char*)Ws + i * 8192 + w * 1024);
    __syncthreads();

#pragma unroll
    for (int s = 0; s < 2; ++s) {
      f16x8 af[4], bf[4];
#pragma unroll
      for (int i = 0; i < 4; ++i)
        af[i] = rd128(Xs, wr + i * 16 + lr, s * 4 + lg);
#pragma unroll
      for (int j = 0; j < 4; ++j)
        bf[j] = rd128(Ws, wc + j * 16 + lr, s * 4 + lg);
#pragma unroll
      for (int i = 0; i < 4; ++i)
#pragma unroll
        for (int j = 0; j < 4; ++j)
          acc[i][j] = MFMA16(af[i], bf[j], acc[i][j]);
    }
  }

#pragma unroll
  for (int i = 0; i < 4; ++i)
#pragma unroll
    for (int j = 0; j < 4; ++j)
#pragma unroll
      for (int r = 0; r < 4; ++r) {
        const int row = m0 + wr + i * 16 + lg * 4 + r;
        const int col = n0 + wc + j * 16 + lr;
        Q[(size_t)row * N + col] = (__fp16)acc[i][j][r];
      }
}

// ---------------------------------------------------------------------------
// Attention v3 (verified r8-r12): block = 4 waves, 128 Q-rows of one (b,h);
// grid 2048. 32KB LDS (K then V), swapped QK^T, in-register P via
// cvt_pk + ds_bpermute.
// ---------------------------------------------------------------------------
__global__ __launch_bounds__(256) void attn_k(
    const __fp16* __restrict__ Q,    // [b*4096][1024]
    const __fp16* __restrict__ Kp,   // [b][256][1024]
    const __fp16* __restrict__ Vpt,  // [b][1024][256]
    float* __restrict__ O) {         // [b*4096][1024] f32
  __shared__ __fp16 KV[256 * 64];    // 32KB: K tile, then V^T tile
  const int t = threadIdx.x;
  const int lane = t & 63, w = t >> 6;
  const int lr = lane & 15, lg = lane >> 4;
  const int bh = blockIdx.x >> 5, rb = blockIdx.x & 31;
  const int b = bh >> 4, h = bh & 15;
  const int m0 = rb * 128 + w * 32;

  const __fp16* Kph = Kp + (size_t)b * 256 * 1024 + h * 64;
  const __fp16* Vph = Vpt + ((size_t)b * 1024 + h * 64) * 256;
  const __fp16* Qh = Q + ((size_t)(b * 4096 + m0)) * 1024 + h * 64;

#pragma unroll
  for (int i = 0; i < 8; ++i) {
    const int kr = (i * 4 + w) * 8 + (lane >> 3);
    gload_lds16(Kph + (size_t)kr * 1024 + (((lane & 7) ^ (kr & 7)) * 8),
                (char*)KV + (i * 4 + w) * 1024);
  }

  f16x8 aq[2][2];
#pragma unroll
  for (int mi = 0; mi < 2; ++mi)
#pragma unroll
    for (int s = 0; s < 2; ++s)
      aq[mi][s] =
          *(const f16x8*)(Qh + (size_t)(mi * 16 + lr) * 1024 + s * 32 + lg * 8);

  __syncthreads();  // K staged

  f32x4 dots[2][16];
#pragma unroll
  for (int mi = 0; mi < 2; ++mi)
#pragma unroll
    for (int jt = 0; jt < 16; ++jt) dots[mi][jt] = (f32x4){0.f, 0.f, 0.f, 0.f};
#pragma unroll
  for (int jt = 0; jt < 16; ++jt) {
    const int r = jt * 16 + lr;
    f16x8 k0 = *(const f16x8*)((const char*)KV + r * 128 + ((lg ^ (r & 7)) * 16));
    f16x8 k1 =
        *(const f16x8*)((const char*)KV + r * 128 + (((4 + lg) ^ (r & 7)) * 16));
    dots[0][jt] = MFMA16(k0, aq[0][0], dots[0][jt]);
    dots[0][jt] = MFMA16(k1, aq[0][1], dots[0][jt]);
    dots[1][jt] = MFMA16(k0, aq[1][0], dots[1][jt]);
    dots[1][jt] = MFMA16(k1, aq[1][1], dots[1][jt]);
  }

  unsigned cpk[2][16][2];
  float smv[2];
#pragma unroll
  for (int mi = 0; mi < 2; ++mi) {
    float mx = -1e30f;
#pragma unroll
    for (int jt = 0; jt < 16; ++jt)
#pragma unroll
      for (int r = 0; r < 4; ++r) mx = fmaxf(mx, dots[mi][jt][r]);
    mx = fmaxf(mx, __shfl_xor(mx, 16, 64));
    mx = fmaxf(mx, __shfl_xor(mx, 32, 64));
    float sm = 0.f;
#pragma unroll
    for (int jt = 0; jt < 16; ++jt) {
#pragma unroll
      for (int r = 0; r < 4; ++r) {
        float p = __expf(dots[mi][jt][r] - mx);
        dots[mi][jt][r] = p;
        sm += p;
      }
      cpk[mi][jt][0] = pk2u(dots[mi][jt][0], dots[mi][jt][1]);
      cpk[mi][jt][1] = pk2u(dots[mi][jt][2], dots[mi][jt][3]);
    }
    sm += __shfl_xor(sm, 16, 64);
    sm += __shfl_xor(sm, 32, 64);
    smv[mi] = sm;
  }

  __syncthreads();  // all waves done reading K

#pragma unroll
  for (int i = 0; i < 8; ++i) {
    const int dd = (i * 4 + w) * 2 + (lane >> 5);
    gload_lds16(Vph + (size_t)dd * 256 + (((lane & 31) ^ (dd & 7)) * 8),
                (char*)KV + (i * 4 + w) * 1024);
  }
  __syncthreads();  // V staged

#pragma unroll
  for (int mi = 0; mi < 2; ++mi) {
    f32x4 o[4];
#pragma unroll
    for (int j = 0; j < 4; ++j) o[j] = (f32x4){0.f, 0.f, 0.f, 0.f};
#pragma unroll
    for (int ks = 0; ks < 8; ++ks) {
      u32x4 wds;
#pragma unroll
      for (int m = 0; m < 4; ++m) {
        const int addr = ((((lane & 16) >> 3) + (m >> 1)) * 16 + lr) * 4;
        const int a0 = __builtin_amdgcn_ds_bpermute(
            addr, (int)cpk[mi][ks * 2][m & 1]);
        const int a1 = __builtin_amdgcn_ds_bpermute(
            addr, (int)cpk[mi][ks * 2 + 1][m & 1]);
        wds[m] = (unsigned)((lg >> 1) ? a1 : a0);
      }
      f16x8 pa = __builtin_bit_cast(f16x8, wds);
#pragma unroll
      for (int jt2 = 0; jt2 < 4; ++jt2) {
        const int dd = jt2 * 16 + lr;
        f16x8 bv = *(const f16x8*)((const char*)KV + dd * 512 +
                                   (((ks * 4 + lg) ^ (dd & 7)) * 16));
        o[jt2] = MFMA16(pa, bv, o[jt2]);
      }
    }

    float rs[4];
#pragma unroll
    for (int r = 0; r < 4; ++r)
      rs[r] = 1.f / __shfl(smv[mi], (lane & 48) + lg * 4 + r, 64);
#pragma unroll
    for (int jt2 = 0; jt2 < 4; ++jt2)
#pragma unroll
      for (int r = 0; r < 4; ++r) {
        const size_t row = (size_t)(b * 4096 + m0 + mi * 16 + lg * 4 + r);
        O[row * 1024 + h * 64 + jt2 * 16 + lr] = o[jt2][r] * rs[r];
      }
  }
}

// ---------------------------------------------------------------------------
extern "C" void kernel_launch(void* const* d_in, const int* in_sizes, int n_in,
                              void* d_out, int out_size, void* d_ws, size_t ws_size,
                              hipStream_t stream) {
  (void)in_sizes; (void)n_in; (void)out_size; (void)ws_size;
  const float* x  = (const float*)d_in[0];
  const float* Wq = (const float*)d_in[1];
  const float* Wk = (const float*)d_in[2];
  const float* Wv = (const float*)d_in[3];
  const float* pk = (const float*)d_in[4];
  const float* pv = (const float*)d_in[5];
  float* out = (float*)d_out;

  // ws layout (f16), ~52.4 MB. Qh region doubles as f16 partials (16.8 MB)
  // for stage1; gemm_q overwrites it after the reduce. Xf16 + XT (33.5 MB
  // each) live in d_out, fully overwritten by attn_k at the end.
  __fp16* Qh  = (__fp16*)d_ws;                       // 16384*1024 f16
  __fp16* WqT = Qh  + (size_t)16384 * 1024;          // 1024*1024 each
  __fp16* WkT = WqT + (size_t)1024 * 1024;
  __fp16* WvT = WkT + (size_t)1024 * 1024;
  __fp16* pkT = WvT + (size_t)1024 * 1024;           // 256*4096 each
  __fp16* pvT = pkT + (size_t)256 * 4096;
  __fp16* Xk  = pvT + (size_t)256 * 4096;            // 4*256*1024 each
  __fp16* Xv  = Xk  + (size_t)4 * 256 * 1024;
  __fp16* Kp  = Xv  + (size_t)4 * 256 * 1024;
  __fp16* Vpt = Kp  + (size_t)4 * 256 * 1024;
  __fp16* Pk16 = (__fp16*)d_ws;                      // 16*256*1024 f16 each
  __fp16* Pv16 = Pk16 + (size_t)16 * 256 * 1024;
  __fp16* Xf16 = (__fp16*)d_out;                     // 4*4096*1024 f16
  __fp16* XT   = Xf16 + (size_t)4 * 4096 * 1024;     // 4*1024*4096 f16

  const dim3 bb(256);

  // 0. all conversions in one launch
  prep<<<dim3(13312), bb, 0, stream>>>(x, Xf16, XT, Wq, Wk, Wv, WqT, WkT, WvT,
                                       pk, pv, pkT, pvT);

  // 1. split-K low-rank projections of X^T + reduce (f16 partials)
  stage1_partial<<<dim3(1024), bb, 0, stream>>>(pkT, pvT, XT, Pk16, Pv16);
  stage1_reduce<<<dim3(512), bb, 0, stream>>>(Pk16, Pv16, Xk, Xv);

  // 2. Kp = Xk . Wk ; VpT = (Xv . Wv)^T  (single launch, BK=64)
  bt64z<<<dim3(512), bb, 0, stream>>>(Xk, WkT, Kp, WvT, Xv, Vpt);

  // 3. Q projection (256x128, 8 waves; overwrites partials region)
  gemm_q<<<dim3(512), dim3(512), 0, stream>>>(Xf16, WqT, Qh);

  // 4. attention (overwrites Xf16/XT = d_out)
  attn_k<<<dim3(2048), bb, 0, stream>>>(Qh, Kp, Vpt, out);
}